// Round 11
// baseline (5749.375 us; speedup 1.0000x reference)
//
#include <hip/hip_runtime.h>

// ---------------------------------------------------------------------------
// Persistent weight-stationary LSTM, bf16 MFMA, decoupled per-layer sync.
// T=1024 B=64 C=256 H=512, 2 layers, fp32 in/out.
// == r11: r10 (5275us) + split-compute overlap + per-wave publish ==
//  - 128 blocks x 256 threads: blocks 0..63 = L0, 64..127 = L1. Block =
//    32 batches (mg half) x 4 col-groups; wave = 1 cg, full K in VGPR.
//  - SPLIT-COMPUTE (new): MFMA kt0..7 (cols 0..255) runs while the second
//    half-tile's loads fly; then write+sync+kt8..15. Removes the ~600cy
//    second-half write stall from the serial path (both layers).
//  - PER-WAVE PUBLISH (new): each wave drains its own vmcnt then lane0 adds
//    to the group line (32 adds/tick/group; 32nd bumps the layer line).
//    Publish no longer waits the block's slowest wave + barrier.
//  - Direct group-line polling, single-poller wave0 + LDS fan-out, split-wait
//    staging, xb pre-pack, zero-shuffle epilogue: all r10, proven.
//  - LDS conflicts ~1e8 are EXPECTED and harmless (r9: fully hidden; fixing
//    them broke global coalescing and cost +1ms).
//  - All spins bounded (r5 lesson): wedge => garbage + verify-fail, no hang.
// ---------------------------------------------------------------------------

#define TT 1024
#define BB 64
#define CC 256
#define HH 512
#define Y_ELEMS (TT * BB * HH)
#define S_ELEMS (BB * HH)
#define RING 4
#define POLL_MAX 8192

typedef __attribute__((ext_vector_type(8))) short bf16x8;
typedef __attribute__((ext_vector_type(4))) float f32x4;
typedef unsigned int u32;
typedef unsigned short u16;
typedef unsigned long long u64;

// ---- ws layout (bytes) ----
#define WS_CNT   0         // group lines [g*16] g=0..15 (0-7 L0, 8-15 L1); layer lines [256]=L0,[272]=L1
#define WS_BSUM0 4096      // 2048 f32
#define WS_BSUM1 12288     // 2048 f32
#define WS_H0R   20480     // RING * 65536 B (h0 ring, bf16; doubles as y0 feed)
#define WS_H1R   282624    // 2 * 65536 B  (h1 ping-pong, bf16)
#define WS_WPK0  413696    // 128*24*64*8 bf16 = 3145728 B
#define WS_WPK1  3559424   // 128*32*64*8 bf16 = 4194304 B
#define WS_XB    7753728   // optional: x as bf16 [T][B][C] = 33554432 B
#define WS_XB_END (WS_XB + (size_t)TT * BB * CC * 2)

__device__ __forceinline__ u16 f2b_rne(float f) {
    u32 u = __float_as_uint(f);
    return (u16)((u + 0x7FFFu + ((u >> 16) & 1u)) >> 16);
}
__device__ __forceinline__ u16 f2b_fast(float f) {
    return (u16)((__float_as_uint(f) + 0x8000u) >> 16);
}
__device__ __forceinline__ float sigf(float z) { return 1.0f / (1.0f + __expf(-z)); }
__device__ __forceinline__ float tanh_f(float z) { return 2.0f / (1.0f + __expf(-2.0f * z)) - 1.0f; }

__device__ __forceinline__ bf16x8 pack8(float4 a, float4 b) {
    union { u16 u[8]; bf16x8 v; } r;
    r.u[0] = f2b_fast(a.x); r.u[1] = f2b_fast(a.y); r.u[2] = f2b_fast(a.z); r.u[3] = f2b_fast(a.w);
    r.u[4] = f2b_fast(b.x); r.u[5] = f2b_fast(b.y); r.u[6] = f2b_fast(b.z); r.u[7] = f2b_fast(b.w);
    return r.v;
}

// ---- MALL (agent, relaxed) accessors ----
__device__ __forceinline__ u64 cload64(const u64* p) {
    return __hip_atomic_load((u64*)p, __ATOMIC_RELAXED, __HIP_MEMORY_SCOPE_AGENT);
}
__device__ __forceinline__ u32 cload32(const u32* p) {
    return __hip_atomic_load((u32*)p, __ATOMIC_RELAXED, __HIP_MEMORY_SCOPE_AGENT);
}
__device__ __forceinline__ void cstore64(u64* p, u64 v) {
    __hip_atomic_store(p, v, __ATOMIC_RELAXED, __HIP_MEMORY_SCOPE_AGENT);
}
__device__ __forceinline__ u32 cadd32(u32* p, u32 v) {
    return __hip_atomic_fetch_add(p, v, __ATOMIC_RELAXED, __HIP_MEMORY_SCOPE_AGENT);
}

// wave0-only MALL poll: lanes lo..lo+3 poll group lines gbase..gbase+3 vs
// needG; lane 8 optionally polls aux (layer line) vs needAux. Bounded.
__device__ __forceinline__ void poll_half(const u32* cnt, int gbase, int lo, u32 needG,
                                          const u32* aux, u32 needAux) {
    const int lane = threadIdx.x & 63;
    const u32* p = (lane >= lo && lane < lo + 4) ? (cnt + (gbase + lane - lo) * 16) : nullptr;
    for (int it = 0; it < POLL_MAX; ++it) {
        int ok = 1;
        if (p) ok = (int)(cload32(p) >= needG);
        if (aux && lane == 8) ok = (int)(cload32(aux) >= needAux);
        if (__ballot(ok) == ~0ull) break;
        __builtin_amdgcn_s_sleep(1);
    }
    asm volatile("" ::: "memory");
}

// LDS flag fan-out (workgroup scope; no MALL traffic)
__device__ __forceinline__ void lds_signal(u32* f, u32 v) {
    __hip_atomic_store(f, v, __ATOMIC_RELEASE, __HIP_MEMORY_SCOPE_WORKGROUP);
}
__device__ __forceinline__ void lds_wait(u32* f, u32 need) {
    for (int it = 0; it < POLL_MAX; ++it) {
        if (__hip_atomic_load(f, __ATOMIC_ACQUIRE, __HIP_MEMORY_SCOPE_WORKGROUP) >= need) break;
        __builtin_amdgcn_s_sleep(0);
    }
    asm volatile("" ::: "memory");
}

// Per-wave publish: caller has drained ITS OWN vmcnt (stores at MALL). Group
// line gets 32 adds/tick (4 waves x 8 blocks); the 32nd finisher of tick t1
// bumps the layer line (layer = 8*t1 when all 8 groups done).
__device__ __forceinline__ void publishW(u32* cnt, int group, int layerline, u32 t1) {
    u32 prev = cadd32(cnt + group * 16, 1u);
    if (prev == 32u * t1 - 1u) cadd32(cnt + layerline, 1u);
}

// Zero-shuffle cell (r8, verified): acc regs ARE the 4 gates of (batch,col).
__device__ __forceinline__ u64 cell4(const f32x4 g4, float bi, float bf_, float bg_,
                                     float bo, float& c, float& hout) {
    float gi = sigf(g4[0] + bi);
    float gf = sigf(g4[1] + bf_);
    float gc = tanh_f(g4[2] + bg_);
    float go = sigf(g4[3] + bo);
    c = gf * c + gi * gc;
    float h = go * tanh_f(c);
    hout = h;
    const int q = (threadIdx.x & 63) >> 4;
    u32 v = (u32)f2b_rne(h);
    u32 p1 = (u32)__shfl_xor((int)v, 16, 64);
    u32 pair = (q & 1) ? (p1 | (v << 16)) : (v | (p1 << 16));
    u32 p2 = (u32)__shfl_xor((int)pair, 32, 64);
    return (q & 2) ? ((u64)p2 | ((u64)pair << 32)) : ((u64)pair | ((u64)p2 << 32));
}

// ---- init: zero counters, bsum = bih+bhh, h inits into ring slots ----
__global__ void k_init(const float* __restrict__ bih0, const float* __restrict__ bhh0,
                       const float* __restrict__ bih1, const float* __restrict__ bhh1,
                       const float* __restrict__ h00, const float* __restrict__ h01,
                       unsigned char* __restrict__ ws) {
    float* bs0 = (float*)(ws + WS_BSUM0);
    float* bs1 = (float*)(ws + WS_BSUM1);
    u16* h0 = (u16*)(ws + WS_H0R) + (RING - 1) * S_ELEMS;  // tick 0 reads slot 3
    u16* h1 = (u16*)(ws + WS_H1R) + S_ELEMS;               // tick 0 reads slot 1
    int t = blockIdx.x * 256 + threadIdx.x;  // 32768 threads
    if (t < 1024) ((u32*)ws)[t] = 0u;
    if (t < 2048) { bs0[t] = bih0[t] + bhh0[t]; bs1[t] = bih1[t] + bhh1[t]; }
    if (t < S_ELEMS) { h0[t] = f2b_rne(h00[t]); h1[t] = f2b_rne(h01[t]); }
}

// ---- x fp32 -> bf16 pre-pack (same layout [T][B][C]) ----
__global__ void k_xprep(const float* __restrict__ x, unsigned char* __restrict__ ws) {
    u16* xb = (u16*)(ws + WS_XB);
    size_t i = ((size_t)blockIdx.x * 256 + threadIdx.x) * 8;
    float4 f0 = *(const float4*)(x + i);
    float4 f1 = *(const float4*)(x + i + 4);
    *(bf16x8*)(xb + i) = pack8(f0, f1);
}

// ---- weight pack: fp32 [4H,K] -> bf16 A-frag order wpk[cg][kt][lane][8] ----
// Swapped row perm (r8): position m (lane&15) -> W row = (m&3)*512 + cg*4 + (m>>2)
// layer0: kt 0..7 = Wih0, 8..23 = Whh0. layer1: kt 0..15 = Wih1, 16..31 = Whh1.
__global__ void k_wprep(const float* __restrict__ Wih0, const float* __restrict__ Whh0,
                        const float* __restrict__ Wih1, const float* __restrict__ Whh1,
                        unsigned char* __restrict__ ws) {
    u16* wpk0 = (u16*)(ws + WS_WPK0);
    u16* wpk1 = (u16*)(ws + WS_WPK1);
    int u = blockIdx.x * 256 + threadIdx.x;  // 458752 threads
    const float* s;
    u16* d;
    if (u < 128 * 24 * 64) {
        int cg = u / (24 * 64);
        int kt = (u >> 6) % 24;
        int lane = u & 63;
        int n = lane & 15, quad = lane >> 4;
        int row = (n & 3) * 512 + cg * 4 + (n >> 2);
        int k = kt * 32 + quad * 8;
        s = (k < 256) ? (Wih0 + (size_t)row * 256 + k) : (Whh0 + (size_t)row * 512 + (k - 256));
        d = wpk0 + (size_t)((cg * 24 + kt) * 64 + lane) * 8;
    } else {
        int v = u - 128 * 24 * 64;
        int cg = v / (32 * 64);
        int kt = (v >> 6) % 32;
        int lane = v & 63;
        int n = lane & 15, quad = lane >> 4;
        int row = (n & 3) * 512 + cg * 4 + (n >> 2);
        int k = kt * 32 + quad * 8;
        s = (k < 512) ? (Wih1 + (size_t)row * 512 + k) : (Whh1 + (size_t)row * 512 + (k - 512));
        d = wpk1 + (size_t)((cg * 32 + kt) * 64 + lane) * 8;
    }
    #pragma unroll
    for (int i = 0; i < 8; ++i) d[i] = f2b_rne(s[i]);
}

// ---- dependency protocol ----
//  Group line g = wave-tick completions of its 8 blocks (32/tick).
//  L0 tick t: L0 groups >= 32t; t>=4: L1 layer >= 8(t-3) (ring slot free)
//  L1 tick t: L0 groups >= 32(t+1); L1 layer >= 8t (h1[t-1] written)
//  Groups 0-3 produce h cols 0..255; groups 4-7 produce cols 256..511.

// Half-stage: 32 rows x 256 cols. Lane-linear, coalesced.
#define STAGE_HALF_LOAD(dst, srcq, cbase)                                   \
    {                                                                       \
        int row0 = tid >> 5, colu = tid & 31;                               \
        _Pragma("unroll")                                                   \
        for (int i = 0; i < 4; ++i) {                                       \
            int row = i * 8 + row0;                                         \
            dst[2 * i]     = cload64(srcq + row * 128 + (cbase + colu) * 2);\
            dst[2 * i + 1] = cload64(srcq + row * 128 + (cbase + colu) * 2 + 1);\
        }                                                                   \
    }
#define STAGE_HALF_WRITE(sm, src, cbase)                                    \
    {                                                                       \
        int row0 = tid >> 5, colu = tid & 31;                               \
        _Pragma("unroll")                                                   \
        for (int i = 0; i < 4; ++i) {                                       \
            int row = i * 8 + row0;                                         \
            union { u64 q[2]; bf16x8 v; } uu;                               \
            uu.q[0] = src[2 * i]; uu.q[1] = src[2 * i + 1];                 \
            *(bf16x8*)&sm[row * 520 + (cbase + colu) * 8] = uu.v;           \
        }                                                                   \
    }

// ============================ layer 0 (64 blocks) ==========================
__device__ void run_l0(const float* __restrict__ x, const float* __restrict__ c0,
                       float* __restrict__ out, unsigned char* __restrict__ ws,
                       int bid, u16* smem, u32* sflag, int use_xb) {
    u32* cnt = (u32*)(ws + WS_CNT);
    const float* bs = (const float*)(ws + WS_BSUM0);
    u16* h0r = (u16*)(ws + WS_H0R);
    const u16* wpk = (const u16*)(ws + WS_WPK0);
    const u16* xb = (const u16*)(ws + WS_XB);

    const int tid = threadIdx.x, lane = tid & 63, wv = tid >> 6;
    const int mg = bid & 1;
    const int cg = (bid >> 1) * 4 + wv;
    const int r16 = lane & 15, quad = lane >> 4, q8 = quad * 8;
    const int col = cg * 4 + quad;

    const float bi = bs[0 * HH + col], bff = bs[1 * HH + col];
    const float bgc = bs[2 * HH + col], bo = bs[3 * HH + col];
    float c[2];
    #pragma unroll
    for (int mt = 0; mt < 2; ++mt)
        c[mt] = c0[(mg * 32 + mt * 16 + r16) * HH + col];

    bf16x8 w[24];
    {
        const u16* wp = wpk + (size_t)(cg * 24 * 64 + lane) * 8;
        #pragma unroll
        for (int kt = 0; kt < 24; ++kt) w[kt] = *(const bf16x8*)(wp + (size_t)kt * 64 * 8);
    }

    for (int t = 0; t < TT; ++t) {
        f32x4 aE[2] = {{0.f,0.f,0.f,0.f},{0.f,0.f,0.f,0.f}};
        f32x4 aO[2] = {{0.f,0.f,0.f,0.f},{0.f,0.f,0.f,0.f}};
        // x projection FIRST (overlaps peers' straggler window)
        if (use_xb) {
            #pragma unroll
            for (int mt = 0; mt < 2; ++mt) {
                const u16* xp = xb + ((size_t)t * BB + mg * 32 + mt * 16 + r16) * CC + q8;
                #pragma unroll
                for (int kt = 0; kt < 8; ++kt) {
                    bf16x8 a = *(const bf16x8*)(xp + kt * 32);
                    if (kt & 1) aO[mt] = __builtin_amdgcn_mfma_f32_16x16x32_bf16(w[kt], a, aO[mt], 0, 0, 0);
                    else        aE[mt] = __builtin_amdgcn_mfma_f32_16x16x32_bf16(w[kt], a, aE[mt], 0, 0, 0);
                }
            }
        } else {
            #pragma unroll
            for (int mt = 0; mt < 2; ++mt) {
                const float* xp = x + ((size_t)t * BB + mg * 32 + mt * 16 + r16) * CC + q8;
                #pragma unroll
                for (int kt = 0; kt < 8; ++kt) {
                    float4 f0 = *(const float4*)(xp + kt * 32);
                    float4 f1 = *(const float4*)(xp + kt * 32 + 4);
                    bf16x8 a = pack8(f0, f1);
                    if (kt & 1) aO[mt] = __builtin_amdgcn_mfma_f32_16x16x32_bf16(w[kt], a, aO[mt], 0, 0, 0);
                    else        aE[mt] = __builtin_amdgcn_mfma_f32_16x16x32_bf16(w[kt], a, aE[mt], 0, 0, 0);
                }
            }
        }
        const u64* srcq = (const u64*)(h0r + (size_t)((t + RING - 1) & (RING - 1)) * S_ELEMS
                                       + (size_t)mg * 32 * HH);
        u64 sa[8], sb[8];
        // wait producers of cols 0..255 (groups 0-3) + L1 ring guard
        if (t) {
            if (wv == 0) {
                const u32* aux = (t >= RING) ? (cnt + 272) : nullptr;
                poll_half(cnt, 0, 0, 32u * (u32)t, aux, 8u * (u32)(t - RING + 1));
                lds_signal(&sflag[0], (u32)t);
            } else lds_wait(&sflag[0], (u32)t);
        }
        STAGE_HALF_LOAD(sa, srcq, 0)
        // wait producers of cols 256..511 (groups 4-7); sa loads fly
        if (t) {
            if (wv == 0) {
                poll_half(cnt, 4, 4, 32u * (u32)t, nullptr, 0u);
                lds_signal(&sflag[1], (u32)t);
            } else lds_wait(&sflag[1], (u32)t);
        }
        STAGE_HALF_WRITE(smem, sa, 0)
        STAGE_HALF_LOAD(sb, srcq, 32)
        __syncthreads();  // first half-tile visible; sb loads fly
        // SPLIT-COMPUTE: kt 0..7 consumes cols 0..255 while sb is in flight
        #pragma unroll
        for (int kt = 0; kt < 8; ++kt)
            #pragma unroll
            for (int mt = 0; mt < 2; ++mt) {
                bf16x8 a = *(const bf16x8*)&smem[(mt * 16 + r16) * 520 + kt * 32 + q8];
                if (kt & 1) aO[mt] = __builtin_amdgcn_mfma_f32_16x16x32_bf16(w[8 + kt], a, aO[mt], 0, 0, 0);
                else        aE[mt] = __builtin_amdgcn_mfma_f32_16x16x32_bf16(w[8 + kt], a, aE[mt], 0, 0, 0);
            }
        STAGE_HALF_WRITE(smem, sb, 32)
        __syncthreads();  // second half-tile visible
        #pragma unroll
        for (int kt = 8; kt < 16; ++kt)
            #pragma unroll
            for (int mt = 0; mt < 2; ++mt) {
                bf16x8 a = *(const bf16x8*)&smem[(mt * 16 + r16) * 520 + kt * 32 + q8];
                if (kt & 1) aO[mt] = __builtin_amdgcn_mfma_f32_16x16x32_bf16(w[8 + kt], a, aO[mt], 0, 0, 0);
                else        aE[mt] = __builtin_amdgcn_mfma_f32_16x16x32_bf16(w[8 + kt], a, aE[mt], 0, 0, 0);
            }
        // epilogue: lane-local gates -> h; pack 4 cols/batch via 2 shfl_xor
        u16* hw = h0r + (size_t)(t & (RING - 1)) * S_ELEMS;
        float hs0, hs1;
        u64 pk0 = cell4(aE[0] + aO[0], bi, bff, bgc, bo, c[0], hs0);
        u64 pk1 = cell4(aE[1] + aO[1], bi, bff, bgc, bo, c[1], hs1);
        if (quad < 2) {
            u64 pk = (quad & 1) ? pk1 : pk0;
            int batch = mg * 32 + quad * 16 + r16;
            cstore64((u64*)(hw + (size_t)batch * HH + cg * 4), pk);
        }
        // PER-WAVE PUBLISH: this wave's stores are at the MALL after vmcnt(0)
        asm volatile("s_waitcnt vmcnt(0)" ::: "memory");
        if (lane == 0) publishW(cnt, bid >> 3, 256, (u32)(t + 1));
        if (t == TT - 1) {
            float* fin = out + Y_ELEMS;
            int b0_ = mg * 32 + r16;
            fin[b0_ * HH + col] = hs0;
            fin[S_ELEMS + b0_ * HH + col] = c[0];
            fin[(b0_ + 16) * HH + col] = hs1;
            fin[S_ELEMS + (b0_ + 16) * HH + col] = c[1];
        }
        __syncthreads();  // LDS reuse barrier before next tick's staging writes
    }
}

// ============================ layer 1 (64 blocks) ==========================
__device__ void run_l1(const float* __restrict__ c0, float* __restrict__ out,
                       unsigned char* __restrict__ ws, int b2, u16* smem, u32* sflag) {
    u32* cnt = (u32*)(ws + WS_CNT);
    const float* bs = (const float*)(ws + WS_BSUM1);
    const u16* h0r = (const u16*)(ws + WS_H0R);
    u16* h1r = (u16*)(ws + WS_H1R);
    const u16* wpk = (const u16*)(ws + WS_WPK1);
    const int TILE1 = 32 * 520;

    const int tid = threadIdx.x, lane = tid & 63, wv = tid >> 6;
    const int mg = b2 & 1;
    const int cg = (b2 >> 1) * 4 + wv;
    const int r16 = lane & 15, quad = lane >> 4, q8 = quad * 8;
    const int col = cg * 4 + quad;

    const float bi = bs[0 * HH + col], bff = bs[1 * HH + col];
    const float bgc = bs[2 * HH + col], bo = bs[3 * HH + col];
    float c[2];
    #pragma unroll
    for (int mt = 0; mt < 2; ++mt)
        c[mt] = c0[(mg * 32 + mt * 16 + r16) * HH + col];

    bf16x8 w[32];
    {
        const u16* wp = wpk + (size_t)(cg * 32 * 64 + lane) * 8;
        #pragma unroll
        for (int kt = 0; kt < 32; ++kt) w[kt] = *(const bf16x8*)(wp + (size_t)kt * 64 * 8);
    }

    for (int t = 0; t < TT; ++t) {
        const u64* sy = (const u64*)(h0r + (size_t)(t & (RING - 1)) * S_ELEMS
                                     + (size_t)mg * 32 * HH);
        const u64* sh = (const u64*)(h1r + (size_t)((t + 1) & 1) * S_ELEMS
                                     + (size_t)mg * 32 * HH);
        u64 ya[8], yb[8], hc[16];
        // wait L0 groups 0-3 at t+1 (y0 cols 0..255) + own layer >= 8t (h1)
        if (wv == 0) {
            poll_half(cnt, 0, 0, 32u * (u32)(t + 1), t ? (cnt + 272) : nullptr, 8u * (u32)t);
            lds_signal(&sflag[0], (u32)(t + 1));
        } else lds_wait(&sflag[0], (u32)(t + 1));
        STAGE_HALF_LOAD(ya, sy, 0)
        // h1[t-1] loads (guarded by own-layer check in poll above)
        #pragma unroll
        for (int i = 0; i < 8; ++i) {
            int ch = i * 256 + tid;
            hc[2 * i]     = cload64(sh + ch * 2);
            hc[2 * i + 1] = cload64(sh + ch * 2 + 1);
        }
        if (wv == 0) {
            poll_half(cnt, 4, 4, 32u * (u32)(t + 1), nullptr, 0u);
            lds_signal(&sflag[1], (u32)(t + 1));
        } else lds_wait(&sflag[1], (u32)(t + 1));
        STAGE_HALF_WRITE(smem, ya, 0)
        STAGE_HALF_LOAD(yb, sy, 32)
        __syncthreads();  // y0 first half visible; yb + hc fly
        f32x4 aE[2] = {{0.f,0.f,0.f,0.f},{0.f,0.f,0.f,0.f}};
        f32x4 aO[2] = {{0.f,0.f,0.f,0.f},{0.f,0.f,0.f,0.f}};
        // SPLIT-COMPUTE: y0 kt 0..7 (cols 0..255) while yb is in flight
        #pragma unroll
        for (int kt = 0; kt < 8; ++kt)
            #pragma unroll
            for (int mt = 0; mt < 2; ++mt) {
                bf16x8 a = *(const bf16x8*)&smem[(mt * 16 + r16) * 520 + kt * 32 + q8];
                if (kt & 1) aO[mt] = __builtin_amdgcn_mfma_f32_16x16x32_bf16(w[kt], a, aO[mt], 0, 0, 0);
                else        aE[mt] = __builtin_amdgcn_mfma_f32_16x16x32_bf16(w[kt], a, aE[mt], 0, 0, 0);
            }
        STAGE_HALF_WRITE(smem, yb, 32)
        __syncthreads();  // y0 second half visible
        #pragma unroll
        for (int kt = 8; kt < 16; ++kt)
            #pragma unroll
            for (int mt = 0; mt < 2; ++mt) {
                bf16x8 a = *(const bf16x8*)&smem[(mt * 16 + r16) * 520 + kt * 32 + q8];
                if (kt & 1) aO[mt] = __builtin_amdgcn_mfma_f32_16x16x32_bf16(w[kt], a, aO[mt], 0, 0, 0);
                else        aE[mt] = __builtin_amdgcn_mfma_f32_16x16x32_bf16(w[kt], a, aE[mt], 0, 0, 0);
            }
        // write h1 tile (hc landed long ago, under the y0 phases)
        #pragma unroll
        for (int i = 0; i < 8; ++i) {
            int ch = i * 256 + tid;
            union { u64 q[2]; bf16x8 v; } uu;
            uu.q[0] = hc[2 * i]; uu.q[1] = hc[2 * i + 1];
            *(bf16x8*)&smem[TILE1 + (ch >> 6) * 520 + (ch & 63) * 8] = uu.v;
        }
        __syncthreads();  // h1 tile visible
        #pragma unroll
        for (int kt = 0; kt < 16; ++kt)
            #pragma unroll
            for (int mt = 0; mt < 2; ++mt) {
                bf16x8 a = *(const bf16x8*)&smem[TILE1 + (mt * 16 + r16) * 520 + kt * 32 + q8];
                if (kt & 1) aO[mt] = __builtin_amdgcn_mfma_f32_16x16x32_bf16(w[16 + kt], a, aO[mt], 0, 0, 0);
                else        aE[mt] = __builtin_amdgcn_mfma_f32_16x16x32_bf16(w[16 + kt], a, aE[mt], 0, 0, 0);
            }
        // epilogue (zero-shuffle)
        u16* hw = h1r + (size_t)(t & 1) * S_ELEMS;
        float hs0, hs1;
        u64 pk0 = cell4(aE[0] + aO[0], bi, bff, bgc, bo, c[0], hs0);
        u64 pk1 = cell4(aE[1] + aO[1], bi, bff, bgc, bo, c[1], hs1);
        if (quad < 2) {
            u64 pk = (quad & 1) ? pk1 : pk0;
            int batch = mg * 32 + quad * 16 + r16;
            cstore64((u64*)(hw + (size_t)batch * HH + cg * 4), pk);
        }
        // PER-WAVE PUBLISH
        asm volatile("s_waitcnt vmcnt(0)" ::: "memory");
        if (lane == 0) publishW(cnt, 8 + (b2 >> 3), 272, (u32)(t + 1));
        // out stores (plain, cached) AFTER publish - off the critical path
        {
            int b0_ = mg * 32 + r16;
            out[(size_t)t * S_ELEMS + b0_ * HH + col] = hs0;
            out[(size_t)t * S_ELEMS + (b0_ + 16) * HH + col] = hs1;
            if (t == TT - 1) {
                float* fin = out + Y_ELEMS + 2 * S_ELEMS;
                fin[b0_ * HH + col] = hs0;
                fin[S_ELEMS + b0_ * HH + col] = c[0];
                fin[(b0_ + 16) * HH + col] = hs1;
                fin[S_ELEMS + (b0_ + 16) * HH + col] = c[1];
            }
        }
        __syncthreads();  // LDS reuse barrier before next tick's staging writes
    }
}

__global__ __launch_bounds__(256, 1) void k_lstm(const float* __restrict__ x,
                                                 const float* __restrict__ c00,
                                                 const float* __restrict__ c01,
                                                 float* __restrict__ out,
                                                 unsigned char* __restrict__ ws,
                                                 int use_xb) {
    __shared__ __align__(16) u16 smem[2 * 32 * 520];  // 66560 B
    __shared__ u32 sflag[2];
    if (threadIdx.x < 2) sflag[threadIdx.x] = 0u;
    __syncthreads();
    const int bid = blockIdx.x;
    if (bid < 64) run_l0(x, c00, out, ws, bid, smem, sflag, use_xb);
    else          run_l1(c01, out, ws, bid - 64, smem, sflag);
}

extern "C" void kernel_launch(void* const* d_in, const int* in_sizes, int n_in,
                              void* d_out, int out_size, void* d_ws, size_t ws_size,
                              hipStream_t stream) {
    const float* x    = (const float*)d_in[0];
    const float* h0_0 = (const float*)d_in[1];
    const float* c0_0 = (const float*)d_in[2];
    const float* h0_1 = (const float*)d_in[3];
    const float* c0_1 = (const float*)d_in[4];
    const float* Wih0 = (const float*)d_in[5];
    const float* Whh0 = (const float*)d_in[6];
    const float* bih0 = (const float*)d_in[7];
    const float* bhh0 = (const float*)d_in[8];
    const float* Wih1 = (const float*)d_in[9];
    const float* Whh1 = (const float*)d_in[10];
    const float* bih1 = (const float*)d_in[11];
    const float* bhh1 = (const float*)d_in[12];
    float* out = (float*)d_out;
    unsigned char* ws = (unsigned char*)d_ws;

    int use_xb = (ws_size >= (size_t)WS_XB_END) ? 1 : 0;
    k_init<<<128, 256, 0, stream>>>(bih0, bhh0, bih1, bhh1, h0_0, h0_1, ws);
    k_wprep<<<1792, 256, 0, stream>>>(Wih0, Whh0, Wih1, Whh1, ws);
    if (use_xb) k_xprep<<<8192, 256, 0, stream>>>(x, ws);
    k_lstm<<<128, 256, 0, stream>>>(x, c0_0, c0_1, out, ws, use_xb);
}

// Round 12
// 5455.955 us; speedup vs baseline: 1.0538x; 1.0538x over previous
//
#include <hip/hip_runtime.h>

// ---------------------------------------------------------------------------
// Persistent weight-stationary LSTM, bf16 MFMA, decoupled per-layer sync.
// T=1024 B=64 C=256 H=512, 2 layers, fp32 in/out.
// == r12: r10 (5275us, proven) + split-compute ONLY ==
//  - 128 blocks x 256 threads: blocks 0..63 = L0, 64..127 = L1. Block =
//    32 batches (mg half) x 4 col-groups; wave = 1 cg, full K in VGPR.
//  - SPLIT-COMPUTE (the one new variable vs r10): MFMA kt0..7 (cols 0..255)
//    runs while the second half-tile's loads fly; then write+sync+kt8..15.
//    Trades the ~600cy second-half write stall for one extra barrier.
//  - Publish: r10's block-level two-level tree (drain-sync + tid0 group add,
//    8 adds/line/tick; 8th finisher bumps the layer line). r11's per-wave
//    publish (32 adds/line/tick) re-triggered the r8 same-line atomic
//    serialization and cost +9% - reverted.
//  - Direct group-line polling, single-poller wave0 + LDS fan-out, split-wait
//    staging, xb pre-pack, zero-shuffle epilogue: all r10, proven.
//  - LDS conflicts ~1e8 are EXPECTED and harmless (r9: fully hidden; fixing
//    them broke global coalescing and cost +1ms).
//  - All spins bounded (r5 lesson): wedge => garbage + verify-fail, no hang.
// ---------------------------------------------------------------------------

#define TT 1024
#define BB 64
#define CC 256
#define HH 512
#define Y_ELEMS (TT * BB * HH)
#define S_ELEMS (BB * HH)
#define RING 4
#define POLL_MAX 8192

typedef __attribute__((ext_vector_type(8))) short bf16x8;
typedef __attribute__((ext_vector_type(4))) float f32x4;
typedef unsigned int u32;
typedef unsigned short u16;
typedef unsigned long long u64;

// ---- ws layout (bytes) ----
#define WS_CNT   0         // group lines [g*16] g=0..15 (0-7 L0, 8-15 L1); layer lines [256]=L0,[272]=L1
#define WS_BSUM0 4096      // 2048 f32
#define WS_BSUM1 12288     // 2048 f32
#define WS_H0R   20480     // RING * 65536 B (h0 ring, bf16; doubles as y0 feed)
#define WS_H1R   282624    // 2 * 65536 B  (h1 ping-pong, bf16)
#define WS_WPK0  413696    // 128*24*64*8 bf16 = 3145728 B
#define WS_WPK1  3559424   // 128*32*64*8 bf16 = 4194304 B
#define WS_XB    7753728   // optional: x as bf16 [T][B][C] = 33554432 B
#define WS_XB_END (WS_XB + (size_t)TT * BB * CC * 2)

__device__ __forceinline__ u16 f2b_rne(float f) {
    u32 u = __float_as_uint(f);
    return (u16)((u + 0x7FFFu + ((u >> 16) & 1u)) >> 16);
}
__device__ __forceinline__ u16 f2b_fast(float f) {
    return (u16)((__float_as_uint(f) + 0x8000u) >> 16);
}
__device__ __forceinline__ float sigf(float z) { return 1.0f / (1.0f + __expf(-z)); }
__device__ __forceinline__ float tanh_f(float z) { return 2.0f / (1.0f + __expf(-2.0f * z)) - 1.0f; }

__device__ __forceinline__ bf16x8 pack8(float4 a, float4 b) {
    union { u16 u[8]; bf16x8 v; } r;
    r.u[0] = f2b_fast(a.x); r.u[1] = f2b_fast(a.y); r.u[2] = f2b_fast(a.z); r.u[3] = f2b_fast(a.w);
    r.u[4] = f2b_fast(b.x); r.u[5] = f2b_fast(b.y); r.u[6] = f2b_fast(b.z); r.u[7] = f2b_fast(b.w);
    return r.v;
}

// ---- MALL (agent, relaxed) accessors ----
__device__ __forceinline__ u64 cload64(const u64* p) {
    return __hip_atomic_load((u64*)p, __ATOMIC_RELAXED, __HIP_MEMORY_SCOPE_AGENT);
}
__device__ __forceinline__ u32 cload32(const u32* p) {
    return __hip_atomic_load((u32*)p, __ATOMIC_RELAXED, __HIP_MEMORY_SCOPE_AGENT);
}
__device__ __forceinline__ void cstore64(u64* p, u64 v) {
    __hip_atomic_store(p, v, __ATOMIC_RELAXED, __HIP_MEMORY_SCOPE_AGENT);
}
__device__ __forceinline__ u32 cadd32(u32* p, u32 v) {
    return __hip_atomic_fetch_add(p, v, __ATOMIC_RELAXED, __HIP_MEMORY_SCOPE_AGENT);
}

// wave0-only MALL poll: lanes lo..lo+3 poll group lines gbase..gbase+3 vs
// needG; lane 8 optionally polls aux (layer line) vs needAux. Bounded.
__device__ __forceinline__ void poll_half(const u32* cnt, int gbase, int lo, u32 needG,
                                          const u32* aux, u32 needAux) {
    const int lane = threadIdx.x & 63;
    const u32* p = (lane >= lo && lane < lo + 4) ? (cnt + (gbase + lane - lo) * 16) : nullptr;
    for (int it = 0; it < POLL_MAX; ++it) {
        int ok = 1;
        if (p) ok = (int)(cload32(p) >= needG);
        if (aux && lane == 8) ok = (int)(cload32(aux) >= needAux);
        if (__ballot(ok) == ~0ull) break;
        __builtin_amdgcn_s_sleep(1);
    }
    asm volatile("" ::: "memory");
}

// LDS flag fan-out (workgroup scope; no MALL traffic)
__device__ __forceinline__ void lds_signal(u32* f, u32 v) {
    __hip_atomic_store(f, v, __ATOMIC_RELEASE, __HIP_MEMORY_SCOPE_WORKGROUP);
}
__device__ __forceinline__ void lds_wait(u32* f, u32 need) {
    for (int it = 0; it < POLL_MAX; ++it) {
        if (__hip_atomic_load(f, __ATOMIC_ACQUIRE, __HIP_MEMORY_SCOPE_WORKGROUP) >= need) break;
        __builtin_amdgcn_s_sleep(0);
    }
    asm volatile("" ::: "memory");
}

// Two-level publish (r7/r10, proven): group add (8 blocks/group, 8 adds/tick);
// the 8th finisher of tick t1 bumps the layer line.
__device__ __forceinline__ void publish(u32* cnt, int group, int layerline, u32 t1) {
    u32 prev = cadd32(cnt + group * 16, 1u);
    if (prev == 8u * t1 - 1u) cadd32(cnt + layerline, 1u);
}

// Zero-shuffle cell (r8, verified): acc regs ARE the 4 gates of (batch,col).
__device__ __forceinline__ u64 cell4(const f32x4 g4, float bi, float bf_, float bg_,
                                     float bo, float& c, float& hout) {
    float gi = sigf(g4[0] + bi);
    float gf = sigf(g4[1] + bf_);
    float gc = tanh_f(g4[2] + bg_);
    float go = sigf(g4[3] + bo);
    c = gf * c + gi * gc;
    float h = go * tanh_f(c);
    hout = h;
    const int q = (threadIdx.x & 63) >> 4;
    u32 v = (u32)f2b_rne(h);
    u32 p1 = (u32)__shfl_xor((int)v, 16, 64);
    u32 pair = (q & 1) ? (p1 | (v << 16)) : (v | (p1 << 16));
    u32 p2 = (u32)__shfl_xor((int)pair, 32, 64);
    return (q & 2) ? ((u64)p2 | ((u64)pair << 32)) : ((u64)pair | ((u64)p2 << 32));
}

// ---- init: zero counters, bsum = bih+bhh, h inits into ring slots ----
__global__ void k_init(const float* __restrict__ bih0, const float* __restrict__ bhh0,
                       const float* __restrict__ bih1, const float* __restrict__ bhh1,
                       const float* __restrict__ h00, const float* __restrict__ h01,
                       unsigned char* __restrict__ ws) {
    float* bs0 = (float*)(ws + WS_BSUM0);
    float* bs1 = (float*)(ws + WS_BSUM1);
    u16* h0 = (u16*)(ws + WS_H0R) + (RING - 1) * S_ELEMS;  // tick 0 reads slot 3
    u16* h1 = (u16*)(ws + WS_H1R) + S_ELEMS;               // tick 0 reads slot 1
    int t = blockIdx.x * 256 + threadIdx.x;  // 32768 threads
    if (t < 1024) ((u32*)ws)[t] = 0u;
    if (t < 2048) { bs0[t] = bih0[t] + bhh0[t]; bs1[t] = bih1[t] + bhh1[t]; }
    if (t < S_ELEMS) { h0[t] = f2b_rne(h00[t]); h1[t] = f2b_rne(h01[t]); }
}

// ---- x fp32 -> bf16 pre-pack (same layout [T][B][C]) ----
__global__ void k_xprep(const float* __restrict__ x, unsigned char* __restrict__ ws) {
    u16* xb = (u16*)(ws + WS_XB);
    size_t i = ((size_t)blockIdx.x * 256 + threadIdx.x) * 8;
    float4 f0 = *(const float4*)(x + i);
    float4 f1 = *(const float4*)(x + i + 4);
    *(bf16x8*)(xb + i) = pack8(f0, f1);
}

// ---- weight pack: fp32 [4H,K] -> bf16 A-frag order wpk[cg][kt][lane][8] ----
// Swapped row perm (r8): position m (lane&15) -> W row = (m&3)*512 + cg*4 + (m>>2)
// layer0: kt 0..7 = Wih0, 8..23 = Whh0. layer1: kt 0..15 = Wih1, 16..31 = Whh1.
__global__ void k_wprep(const float* __restrict__ Wih0, const float* __restrict__ Whh0,
                        const float* __restrict__ Wih1, const float* __restrict__ Whh1,
                        unsigned char* __restrict__ ws) {
    u16* wpk0 = (u16*)(ws + WS_WPK0);
    u16* wpk1 = (u16*)(ws + WS_WPK1);
    int u = blockIdx.x * 256 + threadIdx.x;  // 458752 threads
    const float* s;
    u16* d;
    if (u < 128 * 24 * 64) {
        int cg = u / (24 * 64);
        int kt = (u >> 6) % 24;
        int lane = u & 63;
        int n = lane & 15, quad = lane >> 4;
        int row = (n & 3) * 512 + cg * 4 + (n >> 2);
        int k = kt * 32 + quad * 8;
        s = (k < 256) ? (Wih0 + (size_t)row * 256 + k) : (Whh0 + (size_t)row * 512 + (k - 256));
        d = wpk0 + (size_t)((cg * 24 + kt) * 64 + lane) * 8;
    } else {
        int v = u - 128 * 24 * 64;
        int cg = v / (32 * 64);
        int kt = (v >> 6) % 32;
        int lane = v & 63;
        int n = lane & 15, quad = lane >> 4;
        int row = (n & 3) * 512 + cg * 4 + (n >> 2);
        int k = kt * 32 + quad * 8;
        s = (k < 512) ? (Wih1 + (size_t)row * 512 + k) : (Whh1 + (size_t)row * 512 + (k - 512));
        d = wpk1 + (size_t)((cg * 32 + kt) * 64 + lane) * 8;
    }
    #pragma unroll
    for (int i = 0; i < 8; ++i) d[i] = f2b_rne(s[i]);
}

// ---- dependency protocol (r10) ----
//  Group line g = block-tick completions of its 8 blocks (8/tick).
//  L0 tick t: L0 groups >= 8t; t>=4: L1 layer >= 8(t-3) (ring slot free)
//  L1 tick t: L0 groups >= 8(t+1); L1 layer >= 8t (h1[t-1] written)
//  Groups 0-3 produce h cols 0..255; groups 4-7 produce cols 256..511.

// Half-stage: 32 rows x 256 cols. Lane-linear, coalesced.
#define STAGE_HALF_LOAD(dst, srcq, cbase)                                   \
    {                                                                       \
        int row0 = tid >> 5, colu = tid & 31;                               \
        _Pragma("unroll")                                                   \
        for (int i = 0; i < 4; ++i) {                                       \
            int row = i * 8 + row0;                                         \
            dst[2 * i]     = cload64(srcq + row * 128 + (cbase + colu) * 2);\
            dst[2 * i + 1] = cload64(srcq + row * 128 + (cbase + colu) * 2 + 1);\
        }                                                                   \
    }
#define STAGE_HALF_WRITE(sm, src, cbase)                                    \
    {                                                                       \
        int row0 = tid >> 5, colu = tid & 31;                               \
        _Pragma("unroll")                                                   \
        for (int i = 0; i < 4; ++i) {                                       \
            int row = i * 8 + row0;                                         \
            union { u64 q[2]; bf16x8 v; } uu;                               \
            uu.q[0] = src[2 * i]; uu.q[1] = src[2 * i + 1];                 \
            *(bf16x8*)&sm[row * 520 + (cbase + colu) * 8] = uu.v;           \
        }                                                                   \
    }

// ============================ layer 0 (64 blocks) ==========================
__device__ void run_l0(const float* __restrict__ x, const float* __restrict__ c0,
                       float* __restrict__ out, unsigned char* __restrict__ ws,
                       int bid, u16* smem, u32* sflag, int use_xb) {
    u32* cnt = (u32*)(ws + WS_CNT);
    const float* bs = (const float*)(ws + WS_BSUM0);
    u16* h0r = (u16*)(ws + WS_H0R);
    const u16* wpk = (const u16*)(ws + WS_WPK0);
    const u16* xb = (const u16*)(ws + WS_XB);

    const int tid = threadIdx.x, lane = tid & 63, wv = tid >> 6;
    const int mg = bid & 1;
    const int cg = (bid >> 1) * 4 + wv;
    const int r16 = lane & 15, quad = lane >> 4, q8 = quad * 8;
    const int col = cg * 4 + quad;

    const float bi = bs[0 * HH + col], bff = bs[1 * HH + col];
    const float bgc = bs[2 * HH + col], bo = bs[3 * HH + col];
    float c[2];
    #pragma unroll
    for (int mt = 0; mt < 2; ++mt)
        c[mt] = c0[(mg * 32 + mt * 16 + r16) * HH + col];

    bf16x8 w[24];
    {
        const u16* wp = wpk + (size_t)(cg * 24 * 64 + lane) * 8;
        #pragma unroll
        for (int kt = 0; kt < 24; ++kt) w[kt] = *(const bf16x8*)(wp + (size_t)kt * 64 * 8);
    }

    for (int t = 0; t < TT; ++t) {
        f32x4 aE[2] = {{0.f,0.f,0.f,0.f},{0.f,0.f,0.f,0.f}};
        f32x4 aO[2] = {{0.f,0.f,0.f,0.f},{0.f,0.f,0.f,0.f}};
        // x projection FIRST (overlaps peers' straggler window)
        if (use_xb) {
            #pragma unroll
            for (int mt = 0; mt < 2; ++mt) {
                const u16* xp = xb + ((size_t)t * BB + mg * 32 + mt * 16 + r16) * CC + q8;
                #pragma unroll
                for (int kt = 0; kt < 8; ++kt) {
                    bf16x8 a = *(const bf16x8*)(xp + kt * 32);
                    if (kt & 1) aO[mt] = __builtin_amdgcn_mfma_f32_16x16x32_bf16(w[kt], a, aO[mt], 0, 0, 0);
                    else        aE[mt] = __builtin_amdgcn_mfma_f32_16x16x32_bf16(w[kt], a, aE[mt], 0, 0, 0);
                }
            }
        } else {
            #pragma unroll
            for (int mt = 0; mt < 2; ++mt) {
                const float* xp = x + ((size_t)t * BB + mg * 32 + mt * 16 + r16) * CC + q8;
                #pragma unroll
                for (int kt = 0; kt < 8; ++kt) {
                    float4 f0 = *(const float4*)(xp + kt * 32);
                    float4 f1 = *(const float4*)(xp + kt * 32 + 4);
                    bf16x8 a = pack8(f0, f1);
                    if (kt & 1) aO[mt] = __builtin_amdgcn_mfma_f32_16x16x32_bf16(w[kt], a, aO[mt], 0, 0, 0);
                    else        aE[mt] = __builtin_amdgcn_mfma_f32_16x16x32_bf16(w[kt], a, aE[mt], 0, 0, 0);
                }
            }
        }
        const u64* srcq = (const u64*)(h0r + (size_t)((t + RING - 1) & (RING - 1)) * S_ELEMS
                                       + (size_t)mg * 32 * HH);
        u64 sa[8], sb[8];
        // wait producers of cols 0..255 (groups 0-3) + L1 ring guard
        if (t) {
            if (wv == 0) {
                const u32* aux = (t >= RING) ? (cnt + 272) : nullptr;
                poll_half(cnt, 0, 0, 8u * (u32)t, aux, 8u * (u32)(t - RING + 1));
                lds_signal(&sflag[0], (u32)t);
            } else lds_wait(&sflag[0], (u32)t);
        }
        STAGE_HALF_LOAD(sa, srcq, 0)
        // wait producers of cols 256..511 (groups 4-7); sa loads fly
        if (t) {
            if (wv == 0) {
                poll_half(cnt, 4, 4, 8u * (u32)t, nullptr, 0u);
                lds_signal(&sflag[1], (u32)t);
            } else lds_wait(&sflag[1], (u32)t);
        }
        STAGE_HALF_WRITE(smem, sa, 0)
        STAGE_HALF_LOAD(sb, srcq, 32)
        __syncthreads();  // first half-tile visible; sb loads fly
        // SPLIT-COMPUTE: kt 0..7 consumes cols 0..255 while sb is in flight
        #pragma unroll
        for (int kt = 0; kt < 8; ++kt)
            #pragma unroll
            for (int mt = 0; mt < 2; ++mt) {
                bf16x8 a = *(const bf16x8*)&smem[(mt * 16 + r16) * 520 + kt * 32 + q8];
                if (kt & 1) aO[mt] = __builtin_amdgcn_mfma_f32_16x16x32_bf16(w[8 + kt], a, aO[mt], 0, 0, 0);
                else        aE[mt] = __builtin_amdgcn_mfma_f32_16x16x32_bf16(w[8 + kt], a, aE[mt], 0, 0, 0);
            }
        STAGE_HALF_WRITE(smem, sb, 32)
        __syncthreads();  // second half-tile visible
        #pragma unroll
        for (int kt = 8; kt < 16; ++kt)
            #pragma unroll
            for (int mt = 0; mt < 2; ++mt) {
                bf16x8 a = *(const bf16x8*)&smem[(mt * 16 + r16) * 520 + kt * 32 + q8];
                if (kt & 1) aO[mt] = __builtin_amdgcn_mfma_f32_16x16x32_bf16(w[8 + kt], a, aO[mt], 0, 0, 0);
                else        aE[mt] = __builtin_amdgcn_mfma_f32_16x16x32_bf16(w[8 + kt], a, aE[mt], 0, 0, 0);
            }
        // epilogue: lane-local gates -> h; pack 4 cols/batch via 2 shfl_xor
        u16* hw = h0r + (size_t)(t & (RING - 1)) * S_ELEMS;
        float hs0, hs1;
        u64 pk0 = cell4(aE[0] + aO[0], bi, bff, bgc, bo, c[0], hs0);
        u64 pk1 = cell4(aE[1] + aO[1], bi, bff, bgc, bo, c[1], hs1);
        if (quad < 2) {
            u64 pk = (quad & 1) ? pk1 : pk0;
            int batch = mg * 32 + quad * 16 + r16;
            cstore64((u64*)(hw + (size_t)batch * HH + cg * 4), pk);
        }
        __syncthreads();  // drains all waves' vmcnt -> h stores at MALL (r10)
        if (tid == 0) publish(cnt, bid >> 3, 256, (u32)(t + 1));
        if (t == TT - 1) {
            float* fin = out + Y_ELEMS;
            int b0_ = mg * 32 + r16;
            fin[b0_ * HH + col] = hs0;
            fin[S_ELEMS + b0_ * HH + col] = c[0];
            fin[(b0_ + 16) * HH + col] = hs1;
            fin[S_ELEMS + (b0_ + 16) * HH + col] = c[1];
        }
    }
}

// ============================ layer 1 (64 blocks) ==========================
__device__ void run_l1(const float* __restrict__ c0, float* __restrict__ out,
                       unsigned char* __restrict__ ws, int b2, u16* smem, u32* sflag) {
    u32* cnt = (u32*)(ws + WS_CNT);
    const float* bs = (const float*)(ws + WS_BSUM1);
    const u16* h0r = (const u16*)(ws + WS_H0R);
    u16* h1r = (u16*)(ws + WS_H1R);
    const u16* wpk = (const u16*)(ws + WS_WPK1);
    const int TILE1 = 32 * 520;

    const int tid = threadIdx.x, lane = tid & 63, wv = tid >> 6;
    const int mg = b2 & 1;
    const int cg = (b2 >> 1) * 4 + wv;
    const int r16 = lane & 15, quad = lane >> 4, q8 = quad * 8;
    const int col = cg * 4 + quad;

    const float bi = bs[0 * HH + col], bff = bs[1 * HH + col];
    const float bgc = bs[2 * HH + col], bo = bs[3 * HH + col];
    float c[2];
    #pragma unroll
    for (int mt = 0; mt < 2; ++mt)
        c[mt] = c0[(mg * 32 + mt * 16 + r16) * HH + col];

    bf16x8 w[32];
    {
        const u16* wp = wpk + (size_t)(cg * 32 * 64 + lane) * 8;
        #pragma unroll
        for (int kt = 0; kt < 32; ++kt) w[kt] = *(const bf16x8*)(wp + (size_t)kt * 64 * 8);
    }

    for (int t = 0; t < TT; ++t) {
        const u64* sy = (const u64*)(h0r + (size_t)(t & (RING - 1)) * S_ELEMS
                                     + (size_t)mg * 32 * HH);
        const u64* sh = (const u64*)(h1r + (size_t)((t + 1) & 1) * S_ELEMS
                                     + (size_t)mg * 32 * HH);
        u64 ya[8], yb[8], hc[16];
        // wait L0 groups 0-3 at t+1 (y0 cols 0..255) + own layer >= 8t (h1)
        if (wv == 0) {
            poll_half(cnt, 0, 0, 8u * (u32)(t + 1), t ? (cnt + 272) : nullptr, 8u * (u32)t);
            lds_signal(&sflag[0], (u32)(t + 1));
        } else lds_wait(&sflag[0], (u32)(t + 1));
        STAGE_HALF_LOAD(ya, sy, 0)
        // h1[t-1] loads (guarded by own-layer check in poll above)
        #pragma unroll
        for (int i = 0; i < 8; ++i) {
            int ch = i * 256 + tid;
            hc[2 * i]     = cload64(sh + ch * 2);
            hc[2 * i + 1] = cload64(sh + ch * 2 + 1);
        }
        if (wv == 0) {
            poll_half(cnt, 4, 4, 8u * (u32)(t + 1), nullptr, 0u);
            lds_signal(&sflag[1], (u32)(t + 1));
        } else lds_wait(&sflag[1], (u32)(t + 1));
        STAGE_HALF_WRITE(smem, ya, 0)
        STAGE_HALF_LOAD(yb, sy, 32)
        __syncthreads();  // y0 first half visible; yb + hc fly
        f32x4 aE[2] = {{0.f,0.f,0.f,0.f},{0.f,0.f,0.f,0.f}};
        f32x4 aO[2] = {{0.f,0.f,0.f,0.f},{0.f,0.f,0.f,0.f}};
        // SPLIT-COMPUTE: y0 kt 0..7 (cols 0..255) while yb is in flight
        #pragma unroll
        for (int kt = 0; kt < 8; ++kt)
            #pragma unroll
            for (int mt = 0; mt < 2; ++mt) {
                bf16x8 a = *(const bf16x8*)&smem[(mt * 16 + r16) * 520 + kt * 32 + q8];
                if (kt & 1) aO[mt] = __builtin_amdgcn_mfma_f32_16x16x32_bf16(w[kt], a, aO[mt], 0, 0, 0);
                else        aE[mt] = __builtin_amdgcn_mfma_f32_16x16x32_bf16(w[kt], a, aE[mt], 0, 0, 0);
            }
        STAGE_HALF_WRITE(smem, yb, 32)
        __syncthreads();  // y0 second half visible
        #pragma unroll
        for (int kt = 8; kt < 16; ++kt)
            #pragma unroll
            for (int mt = 0; mt < 2; ++mt) {
                bf16x8 a = *(const bf16x8*)&smem[(mt * 16 + r16) * 520 + kt * 32 + q8];
                if (kt & 1) aO[mt] = __builtin_amdgcn_mfma_f32_16x16x32_bf16(w[kt], a, aO[mt], 0, 0, 0);
                else        aE[mt] = __builtin_amdgcn_mfma_f32_16x16x32_bf16(w[kt], a, aE[mt], 0, 0, 0);
            }
        // write h1 tile (hc landed long ago, under the y0 phases)
        #pragma unroll
        for (int i = 0; i < 8; ++i) {
            int ch = i * 256 + tid;
            union { u64 q[2]; bf16x8 v; } uu;
            uu.q[0] = hc[2 * i]; uu.q[1] = hc[2 * i + 1];
            *(bf16x8*)&smem[TILE1 + (ch >> 6) * 520 + (ch & 63) * 8] = uu.v;
        }
        __syncthreads();  // h1 tile visible
        #pragma unroll
        for (int kt = 0; kt < 16; ++kt)
            #pragma unroll
            for (int mt = 0; mt < 2; ++mt) {
                bf16x8 a = *(const bf16x8*)&smem[TILE1 + (mt * 16 + r16) * 520 + kt * 32 + q8];
                if (kt & 1) aO[mt] = __builtin_amdgcn_mfma_f32_16x16x32_bf16(w[16 + kt], a, aO[mt], 0, 0, 0);
                else        aE[mt] = __builtin_amdgcn_mfma_f32_16x16x32_bf16(w[16 + kt], a, aE[mt], 0, 0, 0);
            }
        // epilogue (zero-shuffle)
        u16* hw = h1r + (size_t)(t & 1) * S_ELEMS;
        float hs0, hs1;
        u64 pk0 = cell4(aE[0] + aO[0], bi, bff, bgc, bo, c[0], hs0);
        u64 pk1 = cell4(aE[1] + aO[1], bi, bff, bgc, bo, c[1], hs1);
        if (quad < 2) {
            u64 pk = (quad & 1) ? pk1 : pk0;
            int batch = mg * 32 + quad * 16 + r16;
            cstore64((u64*)(hw + (size_t)batch * HH + cg * 4), pk);
        }
        __syncthreads();  // drains vmcnt -> h1 stores at MALL (r10)
        if (tid == 0) publish(cnt, 8 + (b2 >> 3), 272, (u32)(t + 1));
        // out stores (plain, cached) AFTER publish - off the critical path
        {
            int b0_ = mg * 32 + r16;
            out[(size_t)t * S_ELEMS + b0_ * HH + col] = hs0;
            out[(size_t)t * S_ELEMS + (b0_ + 16) * HH + col] = hs1;
            if (t == TT - 1) {
                float* fin = out + Y_ELEMS + 2 * S_ELEMS;
                fin[b0_ * HH + col] = hs0;
                fin[S_ELEMS + b0_ * HH + col] = c[0];
                fin[(b0_ + 16) * HH + col] = hs1;
                fin[S_ELEMS + (b0_ + 16) * HH + col] = c[1];
            }
        }
    }
}

__global__ __launch_bounds__(256, 1) void k_lstm(const float* __restrict__ x,
                                                 const float* __restrict__ c00,
                                                 const float* __restrict__ c01,
                                                 float* __restrict__ out,
                                                 unsigned char* __restrict__ ws,
                                                 int use_xb) {
    __shared__ __align__(16) u16 smem[2 * 32 * 520];  // 66560 B
    __shared__ u32 sflag[2];
    if (threadIdx.x < 2) sflag[threadIdx.x] = 0u;
    __syncthreads();
    const int bid = blockIdx.x;
    if (bid < 64) run_l0(x, c00, out, ws, bid, smem, sflag, use_xb);
    else          run_l1(c01, out, ws, bid - 64, smem, sflag);
}

extern "C" void kernel_launch(void* const* d_in, const int* in_sizes, int n_in,
                              void* d_out, int out_size, void* d_ws, size_t ws_size,
                              hipStream_t stream) {
    const float* x    = (const float*)d_in[0];
    const float* h0_0 = (const float*)d_in[1];
    const float* c0_0 = (const float*)d_in[2];
    const float* h0_1 = (const float*)d_in[3];
    const float* c0_1 = (const float*)d_in[4];
    const float* Wih0 = (const float*)d_in[5];
    const float* Whh0 = (const float*)d_in[6];
    const float* bih0 = (const float*)d_in[7];
    const float* bhh0 = (const float*)d_in[8];
    const float* Wih1 = (const float*)d_in[9];
    const float* Whh1 = (const float*)d_in[10];
    const float* bih1 = (const float*)d_in[11];
    const float* bhh1 = (const float*)d_in[12];
    float* out = (float*)d_out;
    unsigned char* ws = (unsigned char*)d_ws;

    int use_xb = (ws_size >= (size_t)WS_XB_END) ? 1 : 0;
    k_init<<<128, 256, 0, stream>>>(bih0, bhh0, bih1, bhh1, h0_0, h0_1, ws);
    k_wprep<<<1792, 256, 0, stream>>>(Wih0, Whh0, Wih1, Whh1, ws);
    if (use_xb) k_xprep<<<8192, 256, 0, stream>>>(x, ws);
    k_lstm<<<128, 256, 0, stream>>>(x, c0_0, c0_1, out, ws, use_xb);
}

// Round 13
// 5324.504 us; speedup vs baseline: 1.0798x; 1.0247x over previous
//
#include <hip/hip_runtime.h>

// ---------------------------------------------------------------------------
// Persistent weight-stationary LSTM, bf16 MFMA, decoupled per-layer sync.
// T=1024 B=64 C=256 H=512, 2 layers, fp32 in/out.
// == FINAL (r10 verbatim, measured 5275us — best of 12 rounds) ==
//  - 128 blocks x 256 threads: blocks 0..63 = L0, 64..127 = L1. Block =
//    32 batches (mg half) x 4 col-groups; wave = 1 cg, full K in VGPR.
//  - Sync: per-block monotonic completion counters, two-level publish tree
//    (8 blocks/group add -> 8th finisher bumps layer line). Consumers poll
//    the 8 producer GROUP lines directly (readiness 1 MALL RTT earlier than
//    the layer line); layer lines serve only the slack guards.
//  - Split-wait staging: wait groups 0-3 -> issue cols 0..255 loads -> wait
//    groups 4-7 (loads fly) -> write/load/write. Single-poller wave0 + LDS
//    flag fan-out (poll traffic contends with awaited stores - r2 lesson).
//  - Zero-shuffle epilogue (operand swap: W = MFMA A operand, gates land in
//    one lane's 4 acc regs). x pre-packed to bf16 (ws-guarded).
//  - Plateau notes (r11/r12 measured): per-wave publish +5% (same-line
//    atomic serialization), split-compute +3.4% (extra barrier > stall it
//    hides; inter-wave TLP already covers it). LDS conflicts 1.007e8 are
//    ds-read lane-aliasing, fully hidden (r9: fixing them broke global
//    coalescing, +1ms). Residual 5.1us/tick = agent-scope handoff chain
//    (drain + publish RTT + detect + stage RTT + straggler variance);
//    XCD-local state would cut it but hung the node twice (r3/r5).
//  - All spins bounded (r5): wedge => garbage + verify-fail, never a hang.
// ---------------------------------------------------------------------------

#define TT 1024
#define BB 64
#define CC 256
#define HH 512
#define Y_ELEMS (TT * BB * HH)
#define S_ELEMS (BB * HH)
#define RING 4
#define POLL_MAX 8192

typedef __attribute__((ext_vector_type(8))) short bf16x8;
typedef __attribute__((ext_vector_type(4))) float f32x4;
typedef unsigned int u32;
typedef unsigned short u16;
typedef unsigned long long u64;

// ---- ws layout (bytes) ----
#define WS_CNT   0         // group lines [g*16] g=0..15 (0-7 L0, 8-15 L1); layer lines [256]=L0,[272]=L1
#define WS_BSUM0 4096      // 2048 f32
#define WS_BSUM1 12288     // 2048 f32
#define WS_H0R   20480     // RING * 65536 B (h0 ring, bf16; doubles as y0 feed)
#define WS_H1R   282624    // 2 * 65536 B  (h1 ping-pong, bf16)
#define WS_WPK0  413696    // 128*24*64*8 bf16 = 3145728 B
#define WS_WPK1  3559424   // 128*32*64*8 bf16 = 4194304 B
#define WS_XB    7753728   // optional: x as bf16 [T][B][C] = 33554432 B
#define WS_XB_END (WS_XB + (size_t)TT * BB * CC * 2)

__device__ __forceinline__ u16 f2b_rne(float f) {
    u32 u = __float_as_uint(f);
    return (u16)((u + 0x7FFFu + ((u >> 16) & 1u)) >> 16);
}
__device__ __forceinline__ u16 f2b_fast(float f) {
    return (u16)((__float_as_uint(f) + 0x8000u) >> 16);
}
__device__ __forceinline__ float sigf(float z) { return 1.0f / (1.0f + __expf(-z)); }
__device__ __forceinline__ float tanh_f(float z) { return 2.0f / (1.0f + __expf(-2.0f * z)) - 1.0f; }

__device__ __forceinline__ bf16x8 pack8(float4 a, float4 b) {
    union { u16 u[8]; bf16x8 v; } r;
    r.u[0] = f2b_fast(a.x); r.u[1] = f2b_fast(a.y); r.u[2] = f2b_fast(a.z); r.u[3] = f2b_fast(a.w);
    r.u[4] = f2b_fast(b.x); r.u[5] = f2b_fast(b.y); r.u[6] = f2b_fast(b.z); r.u[7] = f2b_fast(b.w);
    return r.v;
}

// ---- MALL (agent, relaxed) accessors ----
__device__ __forceinline__ u64 cload64(const u64* p) {
    return __hip_atomic_load((u64*)p, __ATOMIC_RELAXED, __HIP_MEMORY_SCOPE_AGENT);
}
__device__ __forceinline__ u32 cload32(const u32* p) {
    return __hip_atomic_load((u32*)p, __ATOMIC_RELAXED, __HIP_MEMORY_SCOPE_AGENT);
}
__device__ __forceinline__ void cstore64(u64* p, u64 v) {
    __hip_atomic_store(p, v, __ATOMIC_RELAXED, __HIP_MEMORY_SCOPE_AGENT);
}
__device__ __forceinline__ u32 cadd32(u32* p, u32 v) {
    return __hip_atomic_fetch_add(p, v, __ATOMIC_RELAXED, __HIP_MEMORY_SCOPE_AGENT);
}

// wave0-only MALL poll: lanes lo..lo+3 poll group lines gbase..gbase+3 vs
// needG; lane 8 optionally polls aux (layer line) vs needAux. Bounded.
__device__ __forceinline__ void poll_half(const u32* cnt, int gbase, int lo, u32 needG,
                                          const u32* aux, u32 needAux) {
    const int lane = threadIdx.x & 63;
    const u32* p = (lane >= lo && lane < lo + 4) ? (cnt + (gbase + lane - lo) * 16) : nullptr;
    for (int it = 0; it < POLL_MAX; ++it) {
        int ok = 1;
        if (p) ok = (int)(cload32(p) >= needG);
        if (aux && lane == 8) ok = (int)(cload32(aux) >= needAux);
        if (__ballot(ok) == ~0ull) break;
        __builtin_amdgcn_s_sleep(1);
    }
    asm volatile("" ::: "memory");
}

// LDS flag fan-out (workgroup scope; no MALL traffic)
__device__ __forceinline__ void lds_signal(u32* f, u32 v) {
    __hip_atomic_store(f, v, __ATOMIC_RELEASE, __HIP_MEMORY_SCOPE_WORKGROUP);
}
__device__ __forceinline__ void lds_wait(u32* f, u32 need) {
    for (int it = 0; it < POLL_MAX; ++it) {
        if (__hip_atomic_load(f, __ATOMIC_ACQUIRE, __HIP_MEMORY_SCOPE_WORKGROUP) >= need) break;
        __builtin_amdgcn_s_sleep(0);
    }
    asm volatile("" ::: "memory");
}

// Two-level publish (proven): group add; 8th finisher bumps layer line.
__device__ __forceinline__ void publish(u32* cnt, int group, int layerline, u32 t1) {
    u32 prev = cadd32(cnt + group * 16, 1u);
    if (prev == 8u * t1 - 1u) cadd32(cnt + layerline, 1u);
}

// Zero-shuffle cell (r8, verified): acc regs ARE the 4 gates of (batch,col).
__device__ __forceinline__ u64 cell4(const f32x4 g4, float bi, float bf_, float bg_,
                                     float bo, float& c, float& hout) {
    float gi = sigf(g4[0] + bi);
    float gf = sigf(g4[1] + bf_);
    float gc = tanh_f(g4[2] + bg_);
    float go = sigf(g4[3] + bo);
    c = gf * c + gi * gc;
    float h = go * tanh_f(c);
    hout = h;
    const int q = (threadIdx.x & 63) >> 4;
    u32 v = (u32)f2b_rne(h);
    u32 p1 = (u32)__shfl_xor((int)v, 16, 64);
    u32 pair = (q & 1) ? (p1 | (v << 16)) : (v | (p1 << 16));
    u32 p2 = (u32)__shfl_xor((int)pair, 32, 64);
    return (q & 2) ? ((u64)p2 | ((u64)pair << 32)) : ((u64)pair | ((u64)p2 << 32));
}

// ---- init: zero counters, bsum = bih+bhh, h inits into ring slots ----
__global__ void k_init(const float* __restrict__ bih0, const float* __restrict__ bhh0,
                       const float* __restrict__ bih1, const float* __restrict__ bhh1,
                       const float* __restrict__ h00, const float* __restrict__ h01,
                       unsigned char* __restrict__ ws) {
    float* bs0 = (float*)(ws + WS_BSUM0);
    float* bs1 = (float*)(ws + WS_BSUM1);
    u16* h0 = (u16*)(ws + WS_H0R) + (RING - 1) * S_ELEMS;  // tick 0 reads slot 3
    u16* h1 = (u16*)(ws + WS_H1R) + S_ELEMS;               // tick 0 reads slot 1
    int t = blockIdx.x * 256 + threadIdx.x;  // 32768 threads
    if (t < 1024) ((u32*)ws)[t] = 0u;
    if (t < 2048) { bs0[t] = bih0[t] + bhh0[t]; bs1[t] = bih1[t] + bhh1[t]; }
    if (t < S_ELEMS) { h0[t] = f2b_rne(h00[t]); h1[t] = f2b_rne(h01[t]); }
}

// ---- x fp32 -> bf16 pre-pack (same layout [T][B][C]) ----
__global__ void k_xprep(const float* __restrict__ x, unsigned char* __restrict__ ws) {
    u16* xb = (u16*)(ws + WS_XB);
    size_t i = ((size_t)blockIdx.x * 256 + threadIdx.x) * 8;
    float4 f0 = *(const float4*)(x + i);
    float4 f1 = *(const float4*)(x + i + 4);
    *(bf16x8*)(xb + i) = pack8(f0, f1);
}

// ---- weight pack: fp32 [4H,K] -> bf16 A-frag order wpk[cg][kt][lane][8] ----
// Swapped row perm (r8): position m (lane&15) -> W row = (m&3)*512 + cg*4 + (m>>2)
// layer0: kt 0..7 = Wih0, 8..23 = Whh0. layer1: kt 0..15 = Wih1, 16..31 = Whh1.
__global__ void k_wprep(const float* __restrict__ Wih0, const float* __restrict__ Whh0,
                        const float* __restrict__ Wih1, const float* __restrict__ Whh1,
                        unsigned char* __restrict__ ws) {
    u16* wpk0 = (u16*)(ws + WS_WPK0);
    u16* wpk1 = (u16*)(ws + WS_WPK1);
    int u = blockIdx.x * 256 + threadIdx.x;  // 458752 threads
    const float* s;
    u16* d;
    if (u < 128 * 24 * 64) {
        int cg = u / (24 * 64);
        int kt = (u >> 6) % 24;
        int lane = u & 63;
        int n = lane & 15, quad = lane >> 4;
        int row = (n & 3) * 512 + cg * 4 + (n >> 2);
        int k = kt * 32 + quad * 8;
        s = (k < 256) ? (Wih0 + (size_t)row * 256 + k) : (Whh0 + (size_t)row * 512 + (k - 256));
        d = wpk0 + (size_t)((cg * 24 + kt) * 64 + lane) * 8;
    } else {
        int v = u - 128 * 24 * 64;
        int cg = v / (32 * 64);
        int kt = (v >> 6) % 32;
        int lane = v & 63;
        int n = lane & 15, quad = lane >> 4;
        int row = (n & 3) * 512 + cg * 4 + (n >> 2);
        int k = kt * 32 + quad * 8;
        s = (k < 512) ? (Wih1 + (size_t)row * 512 + k) : (Whh1 + (size_t)row * 512 + (k - 512));
        d = wpk1 + (size_t)((cg * 32 + kt) * 64 + lane) * 8;
    }
    #pragma unroll
    for (int i = 0; i < 8; ++i) d[i] = f2b_rne(s[i]);
}

// ---- dependency protocol ----
//  Group line g = block-tick completions of its 8 blocks (8/tick).
//  L0 tick t: L0 groups >= 8t; t>=4: L1 layer >= 8(t-3) (ring slot free)
//  L1 tick t: L0 groups >= 8(t+1); L1 layer >= 8t (h1[t-1] written)
//  Groups 0-3 produce h cols 0..255; groups 4-7 produce cols 256..511.

// Half-stage: 32 rows x 256 cols. Lane-linear, coalesced.
#define STAGE_HALF_LOAD(dst, srcq, cbase)                                   \
    {                                                                       \
        int row0 = tid >> 5, colu = tid & 31;                               \
        _Pragma("unroll")                                                   \
        for (int i = 0; i < 4; ++i) {                                       \
            int row = i * 8 + row0;                                         \
            dst[2 * i]     = cload64(srcq + row * 128 + (cbase + colu) * 2);\
            dst[2 * i + 1] = cload64(srcq + row * 128 + (cbase + colu) * 2 + 1);\
        }                                                                   \
    }
#define STAGE_HALF_WRITE(sm, src, cbase)                                    \
    {                                                                       \
        int row0 = tid >> 5, colu = tid & 31;                               \
        _Pragma("unroll")                                                   \
        for (int i = 0; i < 4; ++i) {                                       \
            int row = i * 8 + row0;                                         \
            union { u64 q[2]; bf16x8 v; } uu;                               \
            uu.q[0] = src[2 * i]; uu.q[1] = src[2 * i + 1];                 \
            *(bf16x8*)&sm[row * 520 + (cbase + colu) * 8] = uu.v;           \
        }                                                                   \
    }

// ============================ layer 0 (64 blocks) ==========================
__device__ void run_l0(const float* __restrict__ x, const float* __restrict__ c0,
                       float* __restrict__ out, unsigned char* __restrict__ ws,
                       int bid, u16* smem, u32* sflag, int use_xb) {
    u32* cnt = (u32*)(ws + WS_CNT);
    const float* bs = (const float*)(ws + WS_BSUM0);
    u16* h0r = (u16*)(ws + WS_H0R);
    const u16* wpk = (const u16*)(ws + WS_WPK0);
    const u16* xb = (const u16*)(ws + WS_XB);

    const int tid = threadIdx.x, lane = tid & 63, wv = tid >> 6;
    const int mg = bid & 1;
    const int cg = (bid >> 1) * 4 + wv;
    const int r16 = lane & 15, quad = lane >> 4, q8 = quad * 8;
    const int col = cg * 4 + quad;

    const float bi = bs[0 * HH + col], bff = bs[1 * HH + col];
    const float bgc = bs[2 * HH + col], bo = bs[3 * HH + col];
    float c[2];
    #pragma unroll
    for (int mt = 0; mt < 2; ++mt)
        c[mt] = c0[(mg * 32 + mt * 16 + r16) * HH + col];

    bf16x8 w[24];
    {
        const u16* wp = wpk + (size_t)(cg * 24 * 64 + lane) * 8;
        #pragma unroll
        for (int kt = 0; kt < 24; ++kt) w[kt] = *(const bf16x8*)(wp + (size_t)kt * 64 * 8);
    }

    for (int t = 0; t < TT; ++t) {
        f32x4 aE[2] = {{0.f,0.f,0.f,0.f},{0.f,0.f,0.f,0.f}};
        f32x4 aO[2] = {{0.f,0.f,0.f,0.f},{0.f,0.f,0.f,0.f}};
        // x projection FIRST (overlaps peers' straggler window)
        if (use_xb) {
            #pragma unroll
            for (int mt = 0; mt < 2; ++mt) {
                const u16* xp = xb + ((size_t)t * BB + mg * 32 + mt * 16 + r16) * CC + q8;
                #pragma unroll
                for (int kt = 0; kt < 8; ++kt) {
                    bf16x8 a = *(const bf16x8*)(xp + kt * 32);
                    if (kt & 1) aO[mt] = __builtin_amdgcn_mfma_f32_16x16x32_bf16(w[kt], a, aO[mt], 0, 0, 0);
                    else        aE[mt] = __builtin_amdgcn_mfma_f32_16x16x32_bf16(w[kt], a, aE[mt], 0, 0, 0);
                }
            }
        } else {
            #pragma unroll
            for (int mt = 0; mt < 2; ++mt) {
                const float* xp = x + ((size_t)t * BB + mg * 32 + mt * 16 + r16) * CC + q8;
                #pragma unroll
                for (int kt = 0; kt < 8; ++kt) {
                    float4 f0 = *(const float4*)(xp + kt * 32);
                    float4 f1 = *(const float4*)(xp + kt * 32 + 4);
                    bf16x8 a = pack8(f0, f1);
                    if (kt & 1) aO[mt] = __builtin_amdgcn_mfma_f32_16x16x32_bf16(w[kt], a, aO[mt], 0, 0, 0);
                    else        aE[mt] = __builtin_amdgcn_mfma_f32_16x16x32_bf16(w[kt], a, aE[mt], 0, 0, 0);
                }
            }
        }
        const u64* srcq = (const u64*)(h0r + (size_t)((t + RING - 1) & (RING - 1)) * S_ELEMS
                                       + (size_t)mg * 32 * HH);
        u64 sa[8], sb[8];
        // wait producers of cols 0..255 (groups 0-3) + L1 ring guard
        if (t) {
            if (wv == 0) {
                const u32* aux = (t >= RING) ? (cnt + 272) : nullptr;
                poll_half(cnt, 0, 0, 8u * (u32)t, aux, 8u * (u32)(t - RING + 1));
                lds_signal(&sflag[0], (u32)t);
            } else lds_wait(&sflag[0], (u32)t);
        }
        STAGE_HALF_LOAD(sa, srcq, 0)
        // wait producers of cols 256..511 (groups 4-7); sa loads fly
        if (t) {
            if (wv == 0) {
                poll_half(cnt, 4, 4, 8u * (u32)t, nullptr, 0u);
                lds_signal(&sflag[1], (u32)t);
            } else lds_wait(&sflag[1], (u32)t);
        }
        STAGE_HALF_WRITE(smem, sa, 0)
        STAGE_HALF_LOAD(sb, srcq, 32)
        STAGE_HALF_WRITE(smem, sb, 32)
        __syncthreads();
        // recurrence MFMAs from LDS
        #pragma unroll
        for (int kt = 0; kt < 16; ++kt)
            #pragma unroll
            for (int mt = 0; mt < 2; ++mt) {
                bf16x8 a = *(const bf16x8*)&smem[(mt * 16 + r16) * 520 + kt * 32 + q8];
                if (kt & 1) aO[mt] = __builtin_amdgcn_mfma_f32_16x16x32_bf16(w[8 + kt], a, aO[mt], 0, 0, 0);
                else        aE[mt] = __builtin_amdgcn_mfma_f32_16x16x32_bf16(w[8 + kt], a, aE[mt], 0, 0, 0);
            }
        // epilogue: lane-local gates -> h; pack 4 cols/batch via 2 shfl_xor
        u16* hw = h0r + (size_t)(t & (RING - 1)) * S_ELEMS;
        float hs0, hs1;
        u64 pk0 = cell4(aE[0] + aO[0], bi, bff, bgc, bo, c[0], hs0);
        u64 pk1 = cell4(aE[1] + aO[1], bi, bff, bgc, bo, c[1], hs1);
        if (quad < 2) {
            u64 pk = (quad & 1) ? pk1 : pk0;
            int batch = mg * 32 + quad * 16 + r16;
            cstore64((u64*)(hw + (size_t)batch * HH + cg * 4), pk);
        }
        __syncthreads();  // drains all waves' vmcnt -> h stores at MALL
        if (tid == 0) publish(cnt, bid >> 3, 256, (u32)(t + 1));
        if (t == TT - 1) {
            float* fin = out + Y_ELEMS;
            int b0_ = mg * 32 + r16;
            fin[b0_ * HH + col] = hs0;
            fin[S_ELEMS + b0_ * HH + col] = c[0];
            fin[(b0_ + 16) * HH + col] = hs1;
            fin[S_ELEMS + (b0_ + 16) * HH + col] = c[1];
        }
    }
}

// ============================ layer 1 (64 blocks) ==========================
__device__ void run_l1(const float* __restrict__ c0, float* __restrict__ out,
                       unsigned char* __restrict__ ws, int b2, u16* smem, u32* sflag) {
    u32* cnt = (u32*)(ws + WS_CNT);
    const float* bs = (const float*)(ws + WS_BSUM1);
    const u16* h0r = (const u16*)(ws + WS_H0R);
    u16* h1r = (u16*)(ws + WS_H1R);
    const u16* wpk = (const u16*)(ws + WS_WPK1);
    const int TILE1 = 32 * 520;

    const int tid = threadIdx.x, lane = tid & 63, wv = tid >> 6;
    const int mg = b2 & 1;
    const int cg = (b2 >> 1) * 4 + wv;
    const int r16 = lane & 15, quad = lane >> 4, q8 = quad * 8;
    const int col = cg * 4 + quad;

    const float bi = bs[0 * HH + col], bff = bs[1 * HH + col];
    const float bgc = bs[2 * HH + col], bo = bs[3 * HH + col];
    float c[2];
    #pragma unroll
    for (int mt = 0; mt < 2; ++mt)
        c[mt] = c0[(mg * 32 + mt * 16 + r16) * HH + col];

    bf16x8 w[32];
    {
        const u16* wp = wpk + (size_t)(cg * 32 * 64 + lane) * 8;
        #pragma unroll
        for (int kt = 0; kt < 32; ++kt) w[kt] = *(const bf16x8*)(wp + (size_t)kt * 64 * 8);
    }

    for (int t = 0; t < TT; ++t) {
        const u64* sy = (const u64*)(h0r + (size_t)(t & (RING - 1)) * S_ELEMS
                                     + (size_t)mg * 32 * HH);
        const u64* sh = (const u64*)(h1r + (size_t)((t + 1) & 1) * S_ELEMS
                                     + (size_t)mg * 32 * HH);
        u64 ya[8], yb[8], hc[16];
        // wait L0 groups 0-3 at t+1 (y0 cols 0..255) + own layer >= 8t (h1)
        if (wv == 0) {
            poll_half(cnt, 0, 0, 8u * (u32)(t + 1), t ? (cnt + 272) : nullptr, 8u * (u32)t);
            lds_signal(&sflag[0], (u32)(t + 1));
        } else lds_wait(&sflag[0], (u32)(t + 1));
        STAGE_HALF_LOAD(ya, sy, 0)
        // h1[t-1] loads (guarded by own-layer check in poll above)
        #pragma unroll
        for (int i = 0; i < 8; ++i) {
            int ch = i * 256 + tid;
            hc[2 * i]     = cload64(sh + ch * 2);
            hc[2 * i + 1] = cload64(sh + ch * 2 + 1);
        }
        if (wv == 0) {
            poll_half(cnt, 4, 4, 8u * (u32)(t + 1), nullptr, 0u);
            lds_signal(&sflag[1], (u32)(t + 1));
        } else lds_wait(&sflag[1], (u32)(t + 1));
        STAGE_HALF_WRITE(smem, ya, 0)
        STAGE_HALF_LOAD(yb, sy, 32)
        STAGE_HALF_WRITE(smem, yb, 32)
        __syncthreads();  // y0 tile visible
        f32x4 aE[2] = {{0.f,0.f,0.f,0.f},{0.f,0.f,0.f,0.f}};
        f32x4 aO[2] = {{0.f,0.f,0.f,0.f},{0.f,0.f,0.f,0.f}};
        #pragma unroll
        for (int kt = 0; kt < 16; ++kt)
            #pragma unroll
            for (int mt = 0; mt < 2; ++mt) {
                bf16x8 a = *(const bf16x8*)&smem[(mt * 16 + r16) * 520 + kt * 32 + q8];
                if (kt & 1) aO[mt] = __builtin_amdgcn_mfma_f32_16x16x32_bf16(w[kt], a, aO[mt], 0, 0, 0);
                else        aE[mt] = __builtin_amdgcn_mfma_f32_16x16x32_bf16(w[kt], a, aE[mt], 0, 0, 0);
            }
        // write h1 tile (loads landed under the y0 MFMAs)
        #pragma unroll
        for (int i = 0; i < 8; ++i) {
            int ch = i * 256 + tid;
            union { u64 q[2]; bf16x8 v; } uu;
            uu.q[0] = hc[2 * i]; uu.q[1] = hc[2 * i + 1];
            *(bf16x8*)&smem[TILE1 + (ch >> 6) * 520 + (ch & 63) * 8] = uu.v;
        }
        __syncthreads();  // h1 tile visible
        #pragma unroll
        for (int kt = 0; kt < 16; ++kt)
            #pragma unroll
            for (int mt = 0; mt < 2; ++mt) {
                bf16x8 a = *(const bf16x8*)&smem[TILE1 + (mt * 16 + r16) * 520 + kt * 32 + q8];
                if (kt & 1) aO[mt] = __builtin_amdgcn_mfma_f32_16x16x32_bf16(w[16 + kt], a, aO[mt], 0, 0, 0);
                else        aE[mt] = __builtin_amdgcn_mfma_f32_16x16x32_bf16(w[16 + kt], a, aE[mt], 0, 0, 0);
            }
        // epilogue (zero-shuffle)
        u16* hw = h1r + (size_t)(t & 1) * S_ELEMS;
        float hs0, hs1;
        u64 pk0 = cell4(aE[0] + aO[0], bi, bff, bgc, bo, c[0], hs0);
        u64 pk1 = cell4(aE[1] + aO[1], bi, bff, bgc, bo, c[1], hs1);
        if (quad < 2) {
            u64 pk = (quad & 1) ? pk1 : pk0;
            int batch = mg * 32 + quad * 16 + r16;
            cstore64((u64*)(hw + (size_t)batch * HH + cg * 4), pk);
        }
        __syncthreads();  // drains vmcnt -> h1 stores at MALL
        if (tid == 0) publish(cnt, 8 + (b2 >> 3), 272, (u32)(t + 1));
        // out stores (plain, cached) AFTER publish - off the critical path
        {
            int b0_ = mg * 32 + r16;
            out[(size_t)t * S_ELEMS + b0_ * HH + col] = hs0;
            out[(size_t)t * S_ELEMS + (b0_ + 16) * HH + col] = hs1;
            if (t == TT - 1) {
                float* fin = out + Y_ELEMS + 2 * S_ELEMS;
                fin[b0_ * HH + col] = hs0;
                fin[S_ELEMS + b0_ * HH + col] = c[0];
                fin[(b0_ + 16) * HH + col] = hs1;
                fin[S_ELEMS + (b0_ + 16) * HH + col] = c[1];
            }
        }
    }
}

__global__ __launch_bounds__(256, 1) void k_lstm(const float* __restrict__ x,
                                                 const float* __restrict__ c00,
                                                 const float* __restrict__ c01,
                                                 float* __restrict__ out,
                                                 unsigned char* __restrict__ ws,
                                                 int use_xb) {
    __shared__ __align__(16) u16 smem[2 * 32 * 520];  // 66560 B
    __shared__ u32 sflag[2];
    if (threadIdx.x < 2) sflag[threadIdx.x] = 0u;
    __syncthreads();
    const int bid = blockIdx.x;
    if (bid < 64) run_l0(x, c00, out, ws, bid, smem, sflag, use_xb);
    else          run_l1(c01, out, ws, bid - 64, smem, sflag);
}

extern "C" void kernel_launch(void* const* d_in, const int* in_sizes, int n_in,
                              void* d_out, int out_size, void* d_ws, size_t ws_size,
                              hipStream_t stream) {
    const float* x    = (const float*)d_in[0];
    const float* h0_0 = (const float*)d_in[1];
    const float* c0_0 = (const float*)d_in[2];
    const float* h0_1 = (const float*)d_in[3];
    const float* c0_1 = (const float*)d_in[4];
    const float* Wih0 = (const float*)d_in[5];
    const float* Whh0 = (const float*)d_in[6];
    const float* bih0 = (const float*)d_in[7];
    const float* bhh0 = (const float*)d_in[8];
    const float* Wih1 = (const float*)d_in[9];
    const float* Whh1 = (const float*)d_in[10];
    const float* bih1 = (const float*)d_in[11];
    const float* bhh1 = (const float*)d_in[12];
    float* out = (float*)d_out;
    unsigned char* ws = (unsigned char*)d_ws;

    int use_xb = (ws_size >= (size_t)WS_XB_END) ? 1 : 0;
    k_init<<<128, 256, 0, stream>>>(bih0, bhh0, bih1, bhh1, h0_0, h0_1, ws);
    k_wprep<<<1792, 256, 0, stream>>>(Wih0, Whh0, Wih1, Whh1, ws);
    if (use_xb) k_xprep<<<8192, 256, 0, stream>>>(x, ws);
    k_lstm<<<128, 256, 0, stream>>>(x, c0_0, c0_1, out, ws, use_xb);
}

// Round 14
// 5238.195 us; speedup vs baseline: 1.0976x; 1.0165x over previous
//
#include <hip/hip_runtime.h>

// ---------------------------------------------------------------------------
// Persistent weight-stationary LSTM, bf16 MFMA, decoupled per-layer sync.
// T=1024 B=64 C=256 H=512, 2 layers, fp32 in/out.
// == FINAL (r10 structure, measured 5275/5324us best-of-session) ==
// r14 change (ONE variable): POLL_MAX 8192 -> 65536. r13's rocprof exposed a
// throttled dispatch where 8192-iteration bounded polls EXPIRED and blocks
// proceeded with stale h (absmax 0.0078->0.0144, one 24.7ms dispatch).
// 65536 tolerates ~20ms of external throttle; a true wedge still terminates
// (bounded) instead of killing the node (r5 lesson).
//  - 128 blocks x 256 threads: blocks 0..63 = L0, 64..127 = L1. Block =
//    32 batches (mg half) x 4 col-groups; wave = 1 cg, full K in VGPR.
//  - Sync: per-block monotonic completion counters, two-level publish tree
//    (8 blocks/group add -> 8th finisher bumps layer line). Consumers poll
//    the 8 producer GROUP lines directly; layer lines serve slack guards.
//  - Split-wait staging, single-poller wave0 + LDS flag fan-out, zero-shuffle
//    epilogue (W as MFMA A operand), x pre-packed to bf16 (ws-guarded).
//  - Plateau (measured): per-wave publish +5% (atomic serialization),
//    split-compute +3.4% (barrier > hidden stall), LDS-conflict fix +1ms
//    (broke global coalescing; the 1.007e8 conflicts are fully hidden).
//    Residual 5.1us/tick = agent-scope handoff latency chain; XCD-local
//    state would cut it but hung the node twice (r3/r5). Not a roofline:
//    MfmaUtil 3.6%, HBM 2.4% - latency-bound by design space, not HW peaks.
// ---------------------------------------------------------------------------

#define TT 1024
#define BB 64
#define CC 256
#define HH 512
#define Y_ELEMS (TT * BB * HH)
#define S_ELEMS (BB * HH)
#define RING 4
#define POLL_MAX 65536

typedef __attribute__((ext_vector_type(8))) short bf16x8;
typedef __attribute__((ext_vector_type(4))) float f32x4;
typedef unsigned int u32;
typedef unsigned short u16;
typedef unsigned long long u64;

// ---- ws layout (bytes) ----
#define WS_CNT   0         // group lines [g*16] g=0..15 (0-7 L0, 8-15 L1); layer lines [256]=L0,[272]=L1
#define WS_BSUM0 4096      // 2048 f32
#define WS_BSUM1 12288     // 2048 f32
#define WS_H0R   20480     // RING * 65536 B (h0 ring, bf16; doubles as y0 feed)
#define WS_H1R   282624    // 2 * 65536 B  (h1 ping-pong, bf16)
#define WS_WPK0  413696    // 128*24*64*8 bf16 = 3145728 B
#define WS_WPK1  3559424   // 128*32*64*8 bf16 = 4194304 B
#define WS_XB    7753728   // optional: x as bf16 [T][B][C] = 33554432 B
#define WS_XB_END (WS_XB + (size_t)TT * BB * CC * 2)

__device__ __forceinline__ u16 f2b_rne(float f) {
    u32 u = __float_as_uint(f);
    return (u16)((u + 0x7FFFu + ((u >> 16) & 1u)) >> 16);
}
__device__ __forceinline__ u16 f2b_fast(float f) {
    return (u16)((__float_as_uint(f) + 0x8000u) >> 16);
}
__device__ __forceinline__ float sigf(float z) { return 1.0f / (1.0f + __expf(-z)); }
__device__ __forceinline__ float tanh_f(float z) { return 2.0f / (1.0f + __expf(-2.0f * z)) - 1.0f; }

__device__ __forceinline__ bf16x8 pack8(float4 a, float4 b) {
    union { u16 u[8]; bf16x8 v; } r;
    r.u[0] = f2b_fast(a.x); r.u[1] = f2b_fast(a.y); r.u[2] = f2b_fast(a.z); r.u[3] = f2b_fast(a.w);
    r.u[4] = f2b_fast(b.x); r.u[5] = f2b_fast(b.y); r.u[6] = f2b_fast(b.z); r.u[7] = f2b_fast(b.w);
    return r.v;
}

// ---- MALL (agent, relaxed) accessors ----
__device__ __forceinline__ u64 cload64(const u64* p) {
    return __hip_atomic_load((u64*)p, __ATOMIC_RELAXED, __HIP_MEMORY_SCOPE_AGENT);
}
__device__ __forceinline__ u32 cload32(const u32* p) {
    return __hip_atomic_load((u32*)p, __ATOMIC_RELAXED, __HIP_MEMORY_SCOPE_AGENT);
}
__device__ __forceinline__ void cstore64(u64* p, u64 v) {
    __hip_atomic_store(p, v, __ATOMIC_RELAXED, __HIP_MEMORY_SCOPE_AGENT);
}
__device__ __forceinline__ u32 cadd32(u32* p, u32 v) {
    return __hip_atomic_fetch_add(p, v, __ATOMIC_RELAXED, __HIP_MEMORY_SCOPE_AGENT);
}

// wave0-only MALL poll: lanes lo..lo+3 poll group lines gbase..gbase+3 vs
// needG; lane 8 optionally polls aux (layer line) vs needAux. Bounded.
__device__ __forceinline__ void poll_half(const u32* cnt, int gbase, int lo, u32 needG,
                                          const u32* aux, u32 needAux) {
    const int lane = threadIdx.x & 63;
    const u32* p = (lane >= lo && lane < lo + 4) ? (cnt + (gbase + lane - lo) * 16) : nullptr;
    for (int it = 0; it < POLL_MAX; ++it) {
        int ok = 1;
        if (p) ok = (int)(cload32(p) >= needG);
        if (aux && lane == 8) ok = (int)(cload32(aux) >= needAux);
        if (__ballot(ok) == ~0ull) break;
        __builtin_amdgcn_s_sleep(1);
    }
    asm volatile("" ::: "memory");
}

// LDS flag fan-out (workgroup scope; no MALL traffic)
__device__ __forceinline__ void lds_signal(u32* f, u32 v) {
    __hip_atomic_store(f, v, __ATOMIC_RELEASE, __HIP_MEMORY_SCOPE_WORKGROUP);
}
__device__ __forceinline__ void lds_wait(u32* f, u32 need) {
    for (int it = 0; it < POLL_MAX; ++it) {
        if (__hip_atomic_load(f, __ATOMIC_ACQUIRE, __HIP_MEMORY_SCOPE_WORKGROUP) >= need) break;
        __builtin_amdgcn_s_sleep(0);
    }
    asm volatile("" ::: "memory");
}

// Two-level publish (proven): group add; 8th finisher bumps layer line.
__device__ __forceinline__ void publish(u32* cnt, int group, int layerline, u32 t1) {
    u32 prev = cadd32(cnt + group * 16, 1u);
    if (prev == 8u * t1 - 1u) cadd32(cnt + layerline, 1u);
}

// Zero-shuffle cell (r8, verified): acc regs ARE the 4 gates of (batch,col).
__device__ __forceinline__ u64 cell4(const f32x4 g4, float bi, float bf_, float bg_,
                                     float bo, float& c, float& hout) {
    float gi = sigf(g4[0] + bi);
    float gf = sigf(g4[1] + bf_);
    float gc = tanh_f(g4[2] + bg_);
    float go = sigf(g4[3] + bo);
    c = gf * c + gi * gc;
    float h = go * tanh_f(c);
    hout = h;
    const int q = (threadIdx.x & 63) >> 4;
    u32 v = (u32)f2b_rne(h);
    u32 p1 = (u32)__shfl_xor((int)v, 16, 64);
    u32 pair = (q & 1) ? (p1 | (v << 16)) : (v | (p1 << 16));
    u32 p2 = (u32)__shfl_xor((int)pair, 32, 64);
    return (q & 2) ? ((u64)p2 | ((u64)pair << 32)) : ((u64)pair | ((u64)p2 << 32));
}

// ---- init: zero counters, bsum = bih+bhh, h inits into ring slots ----
__global__ void k_init(const float* __restrict__ bih0, const float* __restrict__ bhh0,
                       const float* __restrict__ bih1, const float* __restrict__ bhh1,
                       const float* __restrict__ h00, const float* __restrict__ h01,
                       unsigned char* __restrict__ ws) {
    float* bs0 = (float*)(ws + WS_BSUM0);
    float* bs1 = (float*)(ws + WS_BSUM1);
    u16* h0 = (u16*)(ws + WS_H0R) + (RING - 1) * S_ELEMS;  // tick 0 reads slot 3
    u16* h1 = (u16*)(ws + WS_H1R) + S_ELEMS;               // tick 0 reads slot 1
    int t = blockIdx.x * 256 + threadIdx.x;  // 32768 threads
    if (t < 1024) ((u32*)ws)[t] = 0u;
    if (t < 2048) { bs0[t] = bih0[t] + bhh0[t]; bs1[t] = bih1[t] + bhh1[t]; }
    if (t < S_ELEMS) { h0[t] = f2b_rne(h00[t]); h1[t] = f2b_rne(h01[t]); }
}

// ---- x fp32 -> bf16 pre-pack (same layout [T][B][C]) ----
__global__ void k_xprep(const float* __restrict__ x, unsigned char* __restrict__ ws) {
    u16* xb = (u16*)(ws + WS_XB);
    size_t i = ((size_t)blockIdx.x * 256 + threadIdx.x) * 8;
    float4 f0 = *(const float4*)(x + i);
    float4 f1 = *(const float4*)(x + i + 4);
    *(bf16x8*)(xb + i) = pack8(f0, f1);
}

// ---- weight pack: fp32 [4H,K] -> bf16 A-frag order wpk[cg][kt][lane][8] ----
// Swapped row perm (r8): position m (lane&15) -> W row = (m&3)*512 + cg*4 + (m>>2)
// layer0: kt 0..7 = Wih0, 8..23 = Whh0. layer1: kt 0..15 = Wih1, 16..31 = Whh1.
__global__ void k_wprep(const float* __restrict__ Wih0, const float* __restrict__ Whh0,
                        const float* __restrict__ Wih1, const float* __restrict__ Whh1,
                        unsigned char* __restrict__ ws) {
    u16* wpk0 = (u16*)(ws + WS_WPK0);
    u16* wpk1 = (u16*)(ws + WS_WPK1);
    int u = blockIdx.x * 256 + threadIdx.x;  // 458752 threads
    const float* s;
    u16* d;
    if (u < 128 * 24 * 64) {
        int cg = u / (24 * 64);
        int kt = (u >> 6) % 24;
        int lane = u & 63;
        int n = lane & 15, quad = lane >> 4;
        int row = (n & 3) * 512 + cg * 4 + (n >> 2);
        int k = kt * 32 + quad * 8;
        s = (k < 256) ? (Wih0 + (size_t)row * 256 + k) : (Whh0 + (size_t)row * 512 + (k - 256));
        d = wpk0 + (size_t)((cg * 24 + kt) * 64 + lane) * 8;
    } else {
        int v = u - 128 * 24 * 64;
        int cg = v / (32 * 64);
        int kt = (v >> 6) % 32;
        int lane = v & 63;
        int n = lane & 15, quad = lane >> 4;
        int row = (n & 3) * 512 + cg * 4 + (n >> 2);
        int k = kt * 32 + quad * 8;
        s = (k < 512) ? (Wih1 + (size_t)row * 512 + k) : (Whh1 + (size_t)row * 512 + (k - 512));
        d = wpk1 + (size_t)((cg * 32 + kt) * 64 + lane) * 8;
    }
    #pragma unroll
    for (int i = 0; i < 8; ++i) d[i] = f2b_rne(s[i]);
}

// ---- dependency protocol ----
//  Group line g = block-tick completions of its 8 blocks (8/tick).
//  L0 tick t: L0 groups >= 8t; t>=4: L1 layer >= 8(t-3) (ring slot free)
//  L1 tick t: L0 groups >= 8(t+1); L1 layer >= 8t (h1[t-1] written)
//  Groups 0-3 produce h cols 0..255; groups 4-7 produce cols 256..511.

// Half-stage: 32 rows x 256 cols. Lane-linear, coalesced.
#define STAGE_HALF_LOAD(dst, srcq, cbase)                                   \
    {                                                                       \
        int row0 = tid >> 5, colu = tid & 31;                               \
        _Pragma("unroll")                                                   \
        for (int i = 0; i < 4; ++i) {                                       \
            int row = i * 8 + row0;                                         \
            dst[2 * i]     = cload64(srcq + row * 128 + (cbase + colu) * 2);\
            dst[2 * i + 1] = cload64(srcq + row * 128 + (cbase + colu) * 2 + 1);\
        }                                                                   \
    }
#define STAGE_HALF_WRITE(sm, src, cbase)                                    \
    {                                                                       \
        int row0 = tid >> 5, colu = tid & 31;                               \
        _Pragma("unroll")                                                   \
        for (int i = 0; i < 4; ++i) {                                       \
            int row = i * 8 + row0;                                         \
            union { u64 q[2]; bf16x8 v; } uu;                               \
            uu.q[0] = src[2 * i]; uu.q[1] = src[2 * i + 1];                 \
            *(bf16x8*)&sm[row * 520 + (cbase + colu) * 8] = uu.v;           \
        }                                                                   \
    }

// ============================ layer 0 (64 blocks) ==========================
__device__ void run_l0(const float* __restrict__ x, const float* __restrict__ c0,
                       float* __restrict__ out, unsigned char* __restrict__ ws,
                       int bid, u16* smem, u32* sflag, int use_xb) {
    u32* cnt = (u32*)(ws + WS_CNT);
    const float* bs = (const float*)(ws + WS_BSUM0);
    u16* h0r = (u16*)(ws + WS_H0R);
    const u16* wpk = (const u16*)(ws + WS_WPK0);
    const u16* xb = (const u16*)(ws + WS_XB);

    const int tid = threadIdx.x, lane = tid & 63, wv = tid >> 6;
    const int mg = bid & 1;
    const int cg = (bid >> 1) * 4 + wv;
    const int r16 = lane & 15, quad = lane >> 4, q8 = quad * 8;
    const int col = cg * 4 + quad;

    const float bi = bs[0 * HH + col], bff = bs[1 * HH + col];
    const float bgc = bs[2 * HH + col], bo = bs[3 * HH + col];
    float c[2];
    #pragma unroll
    for (int mt = 0; mt < 2; ++mt)
        c[mt] = c0[(mg * 32 + mt * 16 + r16) * HH + col];

    bf16x8 w[24];
    {
        const u16* wp = wpk + (size_t)(cg * 24 * 64 + lane) * 8;
        #pragma unroll
        for (int kt = 0; kt < 24; ++kt) w[kt] = *(const bf16x8*)(wp + (size_t)kt * 64 * 8);
    }

    for (int t = 0; t < TT; ++t) {
        f32x4 aE[2] = {{0.f,0.f,0.f,0.f},{0.f,0.f,0.f,0.f}};
        f32x4 aO[2] = {{0.f,0.f,0.f,0.f},{0.f,0.f,0.f,0.f}};
        // x projection FIRST (overlaps peers' straggler window)
        if (use_xb) {
            #pragma unroll
            for (int mt = 0; mt < 2; ++mt) {
                const u16* xp = xb + ((size_t)t * BB + mg * 32 + mt * 16 + r16) * CC + q8;
                #pragma unroll
                for (int kt = 0; kt < 8; ++kt) {
                    bf16x8 a = *(const bf16x8*)(xp + kt * 32);
                    if (kt & 1) aO[mt] = __builtin_amdgcn_mfma_f32_16x16x32_bf16(w[kt], a, aO[mt], 0, 0, 0);
                    else        aE[mt] = __builtin_amdgcn_mfma_f32_16x16x32_bf16(w[kt], a, aE[mt], 0, 0, 0);
                }
            }
        } else {
            #pragma unroll
            for (int mt = 0; mt < 2; ++mt) {
                const float* xp = x + ((size_t)t * BB + mg * 32 + mt * 16 + r16) * CC + q8;
                #pragma unroll
                for (int kt = 0; kt < 8; ++kt) {
                    float4 f0 = *(const float4*)(xp + kt * 32);
                    float4 f1 = *(const float4*)(xp + kt * 32 + 4);
                    bf16x8 a = pack8(f0, f1);
                    if (kt & 1) aO[mt] = __builtin_amdgcn_mfma_f32_16x16x32_bf16(w[kt], a, aO[mt], 0, 0, 0);
                    else        aE[mt] = __builtin_amdgcn_mfma_f32_16x16x32_bf16(w[kt], a, aE[mt], 0, 0, 0);
                }
            }
        }
        const u64* srcq = (const u64*)(h0r + (size_t)((t + RING - 1) & (RING - 1)) * S_ELEMS
                                       + (size_t)mg * 32 * HH);
        u64 sa[8], sb[8];
        // wait producers of cols 0..255 (groups 0-3) + L1 ring guard
        if (t) {
            if (wv == 0) {
                const u32* aux = (t >= RING) ? (cnt + 272) : nullptr;
                poll_half(cnt, 0, 0, 8u * (u32)t, aux, 8u * (u32)(t - RING + 1));
                lds_signal(&sflag[0], (u32)t);
            } else lds_wait(&sflag[0], (u32)t);
        }
        STAGE_HALF_LOAD(sa, srcq, 0)
        // wait producers of cols 256..511 (groups 4-7); sa loads fly
        if (t) {
            if (wv == 0) {
                poll_half(cnt, 4, 4, 8u * (u32)t, nullptr, 0u);
                lds_signal(&sflag[1], (u32)t);
            } else lds_wait(&sflag[1], (u32)t);
        }
        STAGE_HALF_WRITE(smem, sa, 0)
        STAGE_HALF_LOAD(sb, srcq, 32)
        STAGE_HALF_WRITE(smem, sb, 32)
        __syncthreads();
        // recurrence MFMAs from LDS
        #pragma unroll
        for (int kt = 0; kt < 16; ++kt)
            #pragma unroll
            for (int mt = 0; mt < 2; ++mt) {
                bf16x8 a = *(const bf16x8*)&smem[(mt * 16 + r16) * 520 + kt * 32 + q8];
                if (kt & 1) aO[mt] = __builtin_amdgcn_mfma_f32_16x16x32_bf16(w[8 + kt], a, aO[mt], 0, 0, 0);
                else        aE[mt] = __builtin_amdgcn_mfma_f32_16x16x32_bf16(w[8 + kt], a, aE[mt], 0, 0, 0);
            }
        // epilogue: lane-local gates -> h; pack 4 cols/batch via 2 shfl_xor
        u16* hw = h0r + (size_t)(t & (RING - 1)) * S_ELEMS;
        float hs0, hs1;
        u64 pk0 = cell4(aE[0] + aO[0], bi, bff, bgc, bo, c[0], hs0);
        u64 pk1 = cell4(aE[1] + aO[1], bi, bff, bgc, bo, c[1], hs1);
        if (quad < 2) {
            u64 pk = (quad & 1) ? pk1 : pk0;
            int batch = mg * 32 + quad * 16 + r16;
            cstore64((u64*)(hw + (size_t)batch * HH + cg * 4), pk);
        }
        __syncthreads();  // drains all waves' vmcnt -> h stores at MALL
        if (tid == 0) publish(cnt, bid >> 3, 256, (u32)(t + 1));
        if (t == TT - 1) {
            float* fin = out + Y_ELEMS;
            int b0_ = mg * 32 + r16;
            fin[b0_ * HH + col] = hs0;
            fin[S_ELEMS + b0_ * HH + col] = c[0];
            fin[(b0_ + 16) * HH + col] = hs1;
            fin[S_ELEMS + (b0_ + 16) * HH + col] = c[1];
        }
    }
}

// ============================ layer 1 (64 blocks) ==========================
__device__ void run_l1(const float* __restrict__ c0, float* __restrict__ out,
                       unsigned char* __restrict__ ws, int b2, u16* smem, u32* sflag) {
    u32* cnt = (u32*)(ws + WS_CNT);
    const float* bs = (const float*)(ws + WS_BSUM1);
    const u16* h0r = (const u16*)(ws + WS_H0R);
    u16* h1r = (u16*)(ws + WS_H1R);
    const u16* wpk = (const u16*)(ws + WS_WPK1);
    const int TILE1 = 32 * 520;

    const int tid = threadIdx.x, lane = tid & 63, wv = tid >> 6;
    const int mg = b2 & 1;
    const int cg = (b2 >> 1) * 4 + wv;
    const int r16 = lane & 15, quad = lane >> 4, q8 = quad * 8;
    const int col = cg * 4 + quad;

    const float bi = bs[0 * HH + col], bff = bs[1 * HH + col];
    const float bgc = bs[2 * HH + col], bo = bs[3 * HH + col];
    float c[2];
    #pragma unroll
    for (int mt = 0; mt < 2; ++mt)
        c[mt] = c0[(mg * 32 + mt * 16 + r16) * HH + col];

    bf16x8 w[32];
    {
        const u16* wp = wpk + (size_t)(cg * 32 * 64 + lane) * 8;
        #pragma unroll
        for (int kt = 0; kt < 32; ++kt) w[kt] = *(const bf16x8*)(wp + (size_t)kt * 64 * 8);
    }

    for (int t = 0; t < TT; ++t) {
        const u64* sy = (const u64*)(h0r + (size_t)(t & (RING - 1)) * S_ELEMS
                                     + (size_t)mg * 32 * HH);
        const u64* sh = (const u64*)(h1r + (size_t)((t + 1) & 1) * S_ELEMS
                                     + (size_t)mg * 32 * HH);
        u64 ya[8], yb[8], hc[16];
        // wait L0 groups 0-3 at t+1 (y0 cols 0..255) + own layer >= 8t (h1)
        if (wv == 0) {
            poll_half(cnt, 0, 0, 8u * (u32)(t + 1), t ? (cnt + 272) : nullptr, 8u * (u32)t);
            lds_signal(&sflag[0], (u32)(t + 1));
        } else lds_wait(&sflag[0], (u32)(t + 1));
        STAGE_HALF_LOAD(ya, sy, 0)
        // h1[t-1] loads (guarded by own-layer check in poll above)
        #pragma unroll
        for (int i = 0; i < 8; ++i) {
            int ch = i * 256 + tid;
            hc[2 * i]     = cload64(sh + ch * 2);
            hc[2 * i + 1] = cload64(sh + ch * 2 + 1);
        }
        if (wv == 0) {
            poll_half(cnt, 4, 4, 8u * (u32)(t + 1), nullptr, 0u);
            lds_signal(&sflag[1], (u32)(t + 1));
        } else lds_wait(&sflag[1], (u32)(t + 1));
        STAGE_HALF_WRITE(smem, ya, 0)
        STAGE_HALF_LOAD(yb, sy, 32)
        STAGE_HALF_WRITE(smem, yb, 32)
        __syncthreads();  // y0 tile visible
        f32x4 aE[2] = {{0.f,0.f,0.f,0.f},{0.f,0.f,0.f,0.f}};
        f32x4 aO[2] = {{0.f,0.f,0.f,0.f},{0.f,0.f,0.f,0.f}};
        #pragma unroll
        for (int kt = 0; kt < 16; ++kt)
            #pragma unroll
            for (int mt = 0; mt < 2; ++mt) {
                bf16x8 a = *(const bf16x8*)&smem[(mt * 16 + r16) * 520 + kt * 32 + q8];
                if (kt & 1) aO[mt] = __builtin_amdgcn_mfma_f32_16x16x32_bf16(w[kt], a, aO[mt], 0, 0, 0);
                else        aE[mt] = __builtin_amdgcn_mfma_f32_16x16x32_bf16(w[kt], a, aE[mt], 0, 0, 0);
            }
        // write h1 tile (loads landed under the y0 MFMAs)
        #pragma unroll
        for (int i = 0; i < 8; ++i) {
            int ch = i * 256 + tid;
            union { u64 q[2]; bf16x8 v; } uu;
            uu.q[0] = hc[2 * i]; uu.q[1] = hc[2 * i + 1];
            *(bf16x8*)&smem[TILE1 + (ch >> 6) * 520 + (ch & 63) * 8] = uu.v;
        }
        __syncthreads();  // h1 tile visible
        #pragma unroll
        for (int kt = 0; kt < 16; ++kt)
            #pragma unroll
            for (int mt = 0; mt < 2; ++mt) {
                bf16x8 a = *(const bf16x8*)&smem[TILE1 + (mt * 16 + r16) * 520 + kt * 32 + q8];
                if (kt & 1) aO[mt] = __builtin_amdgcn_mfma_f32_16x16x32_bf16(w[16 + kt], a, aO[mt], 0, 0, 0);
                else        aE[mt] = __builtin_amdgcn_mfma_f32_16x16x32_bf16(w[16 + kt], a, aE[mt], 0, 0, 0);
            }
        // epilogue (zero-shuffle)
        u16* hw = h1r + (size_t)(t & 1) * S_ELEMS;
        float hs0, hs1;
        u64 pk0 = cell4(aE[0] + aO[0], bi, bff, bgc, bo, c[0], hs0);
        u64 pk1 = cell4(aE[1] + aO[1], bi, bff, bgc, bo, c[1], hs1);
        if (quad < 2) {
            u64 pk = (quad & 1) ? pk1 : pk0;
            int batch = mg * 32 + quad * 16 + r16;
            cstore64((u64*)(hw + (size_t)batch * HH + cg * 4), pk);
        }
        __syncthreads();  // drains vmcnt -> h1 stores at MALL
        if (tid == 0) publish(cnt, 8 + (b2 >> 3), 272, (u32)(t + 1));
        // out stores (plain, cached) AFTER publish - off the critical path
        {
            int b0_ = mg * 32 + r16;
            out[(size_t)t * S_ELEMS + b0_ * HH + col] = hs0;
            out[(size_t)t * S_ELEMS + (b0_ + 16) * HH + col] = hs1;
            if (t == TT - 1) {
                float* fin = out + Y_ELEMS + 2 * S_ELEMS;
                fin[b0_ * HH + col] = hs0;
                fin[S_ELEMS + b0_ * HH + col] = c[0];
                fin[(b0_ + 16) * HH + col] = hs1;
                fin[S_ELEMS + (b0_ + 16) * HH + col] = c[1];
            }
        }
    }
}

__global__ __launch_bounds__(256, 1) void k_lstm(const float* __restrict__ x,
                                                 const float* __restrict__ c00,
                                                 const float* __restrict__ c01,
                                                 float* __restrict__ out,
                                                 unsigned char* __restrict__ ws,
                                                 int use_xb) {
    __shared__ __align__(16) u16 smem[2 * 32 * 520];  // 66560 B
    __shared__ u32 sflag[2];
    if (threadIdx.x < 2) sflag[threadIdx.x] = 0u;
    __syncthreads();
    const int bid = blockIdx.x;
    if (bid < 64) run_l0(x, c00, out, ws, bid, smem, sflag, use_xb);
    else          run_l1(c01, out, ws, bid - 64, smem, sflag);
}

extern "C" void kernel_launch(void* const* d_in, const int* in_sizes, int n_in,
                              void* d_out, int out_size, void* d_ws, size_t ws_size,
                              hipStream_t stream) {
    const float* x    = (const float*)d_in[0];
    const float* h0_0 = (const float*)d_in[1];
    const float* c0_0 = (const float*)d_in[2];
    const float* h0_1 = (const float*)d_in[3];
    const float* c0_1 = (const float*)d_in[4];
    const float* Wih0 = (const float*)d_in[5];
    const float* Whh0 = (const float*)d_in[6];
    const float* bih0 = (const float*)d_in[7];
    const float* bhh0 = (const float*)d_in[8];
    const float* Wih1 = (const float*)d_in[9];
    const float* Whh1 = (const float*)d_in[10];
    const float* bih1 = (const float*)d_in[11];
    const float* bhh1 = (const float*)d_in[12];
    float* out = (float*)d_out;
    unsigned char* ws = (unsigned char*)d_ws;

    int use_xb = (ws_size >= (size_t)WS_XB_END) ? 1 : 0;
    k_init<<<128, 256, 0, stream>>>(bih0, bhh0, bih1, bhh1, h0_0, h0_1, ws);
    k_wprep<<<1792, 256, 0, stream>>>(Wih0, Whh0, Wih1, Whh1, ws);
    if (use_xb) k_xprep<<<8192, 256, 0, stream>>>(x, ws);
    k_lstm<<<128, 256, 0, stream>>>(x, c0_0, c0_1, out, ws, use_xb);
}